// Round 3
// baseline (1396.691 us; speedup 1.0000x reference)
//
#include <hip/hip_runtime.h>
#include <hip/hip_bf16.h>

#define NN 100000
#define EE 400000
#define IN_DIM 165
#define HID 128
#define NHEAD 8
#define DHEAD 16
#define C1 64
#define NC 2
#define RROWS 4

typedef const float* fpp;

__device__ __forceinline__ float b2f(__hip_bfloat16 x) { return __bfloat162float(x); }

// ordered-uint encoding for float atomic max
__device__ __forceinline__ unsigned encf(float f) {
    unsigned u = __float_as_uint(f);
    return (u & 0x80000000u) ? ~u : (u | 0x80000000u);
}
__device__ __forceinline__ float decf(unsigned e) {
    return (e & 0x80000000u) ? __uint_as_float(e & 0x7FFFFFFFu) : __uint_as_float(~e);
}

// dot of two u32s each packing two bf16
__device__ __forceinline__ float dot2(unsigned a, unsigned b) {
    float al = __uint_as_float(a << 16), ah = __uint_as_float(a & 0xFFFF0000u);
    float bl = __uint_as_float(b << 16), bh = __uint_as_float(b & 0xFFFF0000u);
    return al * bl + ah * bh;
}

// h[N,128] = x[N,165] @ W[165,128] + b   (fp32 out)
__global__ void k_linear_in(fpp x, fpp W, fpp b, float* __restrict__ h, int n) {
    __shared__ float xs[RROWS][IN_DIM];
    int row0 = blockIdx.x * RROWS;
    int col = threadIdx.x;  // 0..127
    for (int r = 0; r < RROWS; r++) {
        int row = row0 + r;
        if (row < n)
            for (int i = col; i < IN_DIM; i += 128)
                xs[r][i] = x[(size_t)row * IN_DIM + i];
    }
    __syncthreads();
    float bb = b[col];
    float acc[RROWS];
    for (int r = 0; r < RROWS; r++) acc[r] = bb;
    for (int k = 0; k < IN_DIM; k++) {
        float w = W[k * HID + col];
        for (int r = 0; r < RROWS; r++) acc[r] += xs[r][k] * w;
    }
    for (int r = 0; r < RROWS; r++) {
        int row = row0 + r;
        if (row < n) h[(size_t)row * HID + col] = acc[r];
    }
}

// q,k = h @ {Wq,Wk} + {bq,bk}   (bf16 out, internal)
__global__ void k_qk(const float* __restrict__ h, fpp Wq, fpp bq, fpp Wk, fpp bk,
                     __hip_bfloat16* __restrict__ qb, __hip_bfloat16* __restrict__ kb,
                     int n) {
    __shared__ float hs[RROWS][HID];
    int row0 = blockIdx.x * RROWS;
    int col = threadIdx.x;
    for (int r = 0; r < RROWS; r++) {
        int row = row0 + r;
        if (row < n) hs[r][col] = h[(size_t)row * HID + col];
    }
    __syncthreads();
    float aq[RROWS], ak[RROWS];
    float bq_ = bq[col], bk_ = bk[col];
    for (int r = 0; r < RROWS; r++) { aq[r] = bq_; ak[r] = bk_; }
    for (int t = 0; t < HID; t++) {
        float wq = Wq[t * HID + col];
        float wk = Wk[t * HID + col];
        for (int r = 0; r < RROWS; r++) {
            float hv = hs[r][t];
            aq[r] += hv * wq; ak[r] += hv * wk;
        }
    }
    for (int r = 0; r < RROWS; r++) {
        int row = row0 + r;
        if (row < n) {
            size_t o = (size_t)row * HID + col;
            qb[o] = __float2bfloat16(aq[r]);
            kb[o] = __float2bfloat16(ak[r]);
        }
    }
}

// v = h @ Wv + bv (bf16 out, internal);  agg = h @ Ws + bs (fp32 out)
__global__ void k_v_skip(const float* __restrict__ h, fpp Wv, fpp bv, fpp Ws, fpp bs,
                         __hip_bfloat16* __restrict__ vb, float* __restrict__ agg, int n) {
    __shared__ float hs[RROWS][HID];
    int row0 = blockIdx.x * RROWS;
    int col = threadIdx.x;
    for (int r = 0; r < RROWS; r++) {
        int row = row0 + r;
        if (row < n) hs[r][col] = h[(size_t)row * HID + col];
    }
    __syncthreads();
    float av[RROWS], as_[RROWS];
    float bv_ = bv[col], bs_ = bs[col];
    for (int r = 0; r < RROWS; r++) { av[r] = bv_; as_[r] = bs_; }
    for (int t = 0; t < HID; t++) {
        float wv = Wv[t * HID + col];
        float ws = Ws[t * HID + col];
        for (int r = 0; r < RROWS; r++) {
            float hv = hs[r][t];
            av[r] += hv * wv; as_[r] += hv * ws;
        }
    }
    for (int r = 0; r < RROWS; r++) {
        int row = row0 + r;
        if (row < n) {
            size_t o = (size_t)row * HID + col;
            vb[o] = __float2bfloat16(av[r]);
            agg[o] = as_[r];
        }
    }
}

__global__ void k_init_seg(unsigned* __restrict__ amax_bits, float* __restrict__ denom) {
    int i = blockIdx.x * blockDim.x + threadIdx.x;
    if (i < NN * NHEAD) { amax_bits[i] = 0x007FFFFFu; denom[i] = 0.f; }  // enc(-inf)
}

__global__ void k_edge_alpha(const __hip_bfloat16* __restrict__ qb,
                             const __hip_bfloat16* __restrict__ kb,
                             const int* __restrict__ src, const int* __restrict__ dst,
                             float* __restrict__ alpha, unsigned* __restrict__ amax_bits) {
    int idx = blockIdx.x * blockDim.x + threadIdx.x;
    if (idx >= EE * NHEAD) return;
    int e = idx >> 3, head = idx & 7;
    int s = src[e], d = dst[e];
    const uint4* qp = (const uint4*)(qb + (size_t)d * HID + head * DHEAD);
    const uint4* kp = (const uint4*)(kb + (size_t)s * HID + head * DHEAD);
    float acc = 0.f;
#pragma unroll
    for (int i = 0; i < 2; i++) {
        uint4 a = qp[i], b = kp[i];
        acc += dot2(a.x, b.x) + dot2(a.y, b.y) + dot2(a.z, b.z) + dot2(a.w, b.w);
    }
    acc *= 0.25f;  // 1/sqrt(16)
    alpha[idx] = acc;
    atomicMax(&amax_bits[d * NHEAD + head], encf(acc));
}

__global__ void k_amax_fin(unsigned* __restrict__ amax_bits) {
    int i = blockIdx.x * blockDim.x + threadIdx.x;
    if (i < NN * NHEAD) {
        float f = decf(amax_bits[i]);
        if (!isfinite(f)) f = 0.f;
        ((float*)amax_bits)[i] = f;
    }
}

__global__ void k_edge_exp(float* __restrict__ alpha, const float* __restrict__ amax,
                           const int* __restrict__ dst, float* __restrict__ denom) {
    int idx = blockIdx.x * blockDim.x + threadIdx.x;
    if (idx >= EE * NHEAD) return;
    int e = idx >> 3, head = idx & 7;
    int d = dst[e];
    float ex = expf(alpha[idx] - amax[d * NHEAD + head]);
    alpha[idx] = ex;
    atomicAdd(&denom[d * NHEAD + head], ex);
}

__global__ void k_edge_msg(const float* __restrict__ alpha, const float* __restrict__ denom,
                           const __hip_bfloat16* __restrict__ vb, const int* __restrict__ src,
                           const int* __restrict__ dst, float* __restrict__ agg) {
    int idx = blockIdx.x * blockDim.x + threadIdx.x;
    if (idx >= EE * HID) return;
    int e = idx >> 7, col = idx & 127;
    int s = src[e], d = dst[e];
    int hh = col >> 4;
    float a = alpha[e * NHEAD + hh] / (denom[d * NHEAD + hh] + 1e-16f);
    atomicAdd(&agg[(size_t)d * HID + col], b2f(vb[(size_t)s * HID + col]) * a);
}

// h = layer_norm(h + agg) * g + b   (in place, one wave per row)
__global__ void k_add_ln(float* __restrict__ h, const float* __restrict__ agg,
                         fpp g, fpp b) {
    int row = blockIdx.x;
    int lane = threadIdx.x;  // 0..63
    size_t o = (size_t)row * HID;
    float v0 = h[o + lane] + agg[o + lane];
    float v1 = h[o + lane + 64] + agg[o + lane + 64];
    float s = v0 + v1, s2 = v0 * v0 + v1 * v1;
    for (int off = 32; off; off >>= 1) {
        s += __shfl_xor(s, off, 64);
        s2 += __shfl_xor(s2, off, 64);
    }
    float m = s * (1.f / HID);
    float var = s2 * (1.f / HID) - m * m;
    float inv = rsqrtf(var + 1e-5f);
    h[o + lane] = (v0 - m) * inv * g[lane] + b[lane];
    h[o + lane + 64] = (v1 - m) * inv * g[lane + 64] + b[lane + 64];
}

// out = relu(h@Wc1+bc1) @ Wc2 + bc2, one wave per row (fp32 out)
__global__ void k_classifier(const float* __restrict__ h, fpp Wc1, fpp bc1, fpp Wc2,
                             fpp bc2, float* __restrict__ out) {
    __shared__ float hs[HID];
    int row = blockIdx.x;
    int t = threadIdx.x;  // 0..63
    hs[t] = h[(size_t)row * HID + t];
    hs[t + 64] = h[(size_t)row * HID + t + 64];
    __syncthreads();
    float acc = bc1[t];
    for (int k = 0; k < HID; k++) acc += hs[k] * Wc1[k * C1 + t];
    acc = fmaxf(acc, 0.f);
    float p0 = acc * Wc2[t * NC + 0];
    float p1 = acc * Wc2[t * NC + 1];
    for (int off = 32; off; off >>= 1) {
        p0 += __shfl_xor(p0, off, 64);
        p1 += __shfl_xor(p1, off, 64);
    }
    if (t == 0) {
        out[(size_t)row * NC + 0] = p0 + bc2[0];
        out[(size_t)row * NC + 1] = p1 + bc2[1];
    }
}

extern "C" void kernel_launch(void* const* d_in, const int* in_sizes, int n_in,
                              void* d_out, int out_size, void* d_ws, size_t ws_size,
                              hipStream_t stream) {
    fpp x = (fpp)d_in[0];
    const int* ei = (const int*)d_in[1];
    const int* src = ei;
    const int* dst = ei + EE;
    fpp W_in = (fpp)d_in[2];  fpp b_in = (fpp)d_in[3];
    fpp Wq1 = (fpp)d_in[4];   fpp bq1 = (fpp)d_in[5];
    fpp Wk1 = (fpp)d_in[6];   fpp bk1 = (fpp)d_in[7];
    fpp Wv1 = (fpp)d_in[8];   fpp bv1 = (fpp)d_in[9];
    fpp Ws1 = (fpp)d_in[10];  fpp bs1 = (fpp)d_in[11];
    fpp g1 = (fpp)d_in[12];   fpp be1 = (fpp)d_in[13];
    fpp Wq2 = (fpp)d_in[14];  fpp bq2 = (fpp)d_in[15];
    fpp Wk2 = (fpp)d_in[16];  fpp bk2 = (fpp)d_in[17];
    fpp Wv2 = (fpp)d_in[18];  fpp bv2 = (fpp)d_in[19];
    fpp Ws2 = (fpp)d_in[20];  fpp bs2 = (fpp)d_in[21];
    fpp g2 = (fpp)d_in[22];   fpp be2 = (fpp)d_in[23];
    fpp Wc1 = (fpp)d_in[24];  fpp bc1 = (fpp)d_in[25];
    fpp Wc2 = (fpp)d_in[26];  fpp bc2 = (fpp)d_in[27];
    float* out = (float*)d_out;

    // workspace layout (172.8 MB total)
    float* ws = (float*)d_ws;
    float* h = ws;                                  // 12.8M fp32
    float* agg = h + (size_t)NN * HID;              // 12.8M fp32
    float* alpha = agg + (size_t)NN * HID;          // 3.2M fp32
    unsigned* amax_bits = (unsigned*)(alpha + (size_t)EE * NHEAD);  // 0.8M
    float* denom = (float*)(amax_bits + (size_t)NN * NHEAD);        // 0.8M
    __hip_bfloat16* qb = (__hip_bfloat16*)(denom + (size_t)NN * NHEAD);  // 12.8M bf16
    __hip_bfloat16* kb = qb + (size_t)NN * HID;                          // 12.8M bf16
    __hip_bfloat16* vb = qb;  // v reuses q's space (q dead after edge_alpha)

    const int nbd = (NN + RROWS - 1) / RROWS;
    const int nseg = (NN * NHEAD + 255) / 256;
    const int nedge = (EE * NHEAD + 255) / 256;
    const int nmsg = (EE * HID + 255) / 256;

    k_linear_in<<<nbd, 128, 0, stream>>>(x, W_in, b_in, h, NN);

    for (int layer = 0; layer < 2; layer++) {
        fpp Wq = layer ? Wq2 : Wq1, bq = layer ? bq2 : bq1;
        fpp Wk = layer ? Wk2 : Wk1, bk = layer ? bk2 : bk1;
        fpp Wv = layer ? Wv2 : Wv1, bv = layer ? bv2 : bv1;
        fpp Wss = layer ? Ws2 : Ws1, bss = layer ? bs2 : bs1;
        fpp g = layer ? g2 : g1, be = layer ? be2 : be1;

        k_qk<<<nbd, 128, 0, stream>>>(h, Wq, bq, Wk, bk, qb, kb, NN);
        k_init_seg<<<nseg, 256, 0, stream>>>(amax_bits, denom);
        k_edge_alpha<<<nedge, 256, 0, stream>>>(qb, kb, src, dst, alpha, amax_bits);
        k_amax_fin<<<nseg, 256, 0, stream>>>(amax_bits);
        // v overwrites q's buffer — q is dead after k_edge_alpha
        k_v_skip<<<nbd, 128, 0, stream>>>(h, Wv, bv, Wss, bss, vb, agg, NN);
        k_edge_exp<<<nedge, 256, 0, stream>>>(alpha, (const float*)amax_bits, dst, denom);
        k_edge_msg<<<nmsg, 256, 0, stream>>>(alpha, denom, vb, src, dst, agg);
        k_add_ln<<<NN, 64, 0, stream>>>(h, agg, g, be);
    }

    k_classifier<<<NN, 64, 0, stream>>>(h, Wc1, bc1, Wc2, bc2, out);
}

// Round 4
// 1128.511 us; speedup vs baseline: 1.2376x; 1.2376x over previous
//
#include <hip/hip_runtime.h>
#include <hip/hip_bf16.h>

#define NN 100000
#define EE 400000
#define IN_DIM 165
#define HID 128
#define NHEAD 8
#define DHEAD 16
#define C1 64
#define NC 2
#define RROWS 4
#define SCANB 256
#define NBLK 391  // ceil(100000/256)

typedef const float* fpp;
typedef __hip_bfloat16 bf16;

__device__ __forceinline__ float bflo(unsigned u) { return __uint_as_float(u << 16); }
__device__ __forceinline__ float bfhi(unsigned u) { return __uint_as_float(u & 0xFFFF0000u); }
__device__ __forceinline__ unsigned short bfbits(float f) {
    bf16 h = __float2bfloat16(f);
    return *reinterpret_cast<unsigned short*>(&h);
}

// ---------------- CSR build ----------------
__global__ void k_deg_zero(int* __restrict__ deg) {
    int i = blockIdx.x * blockDim.x + threadIdx.x;
    if (i < NN) deg[i] = 0;
}
__global__ void k_hist(const int* __restrict__ dst, int* __restrict__ deg) {
    int e = blockIdx.x * blockDim.x + threadIdx.x;
    if (e < EE) atomicAdd(&deg[dst[e]], 1);
}
__global__ void k_scan1(const int* __restrict__ deg, int* __restrict__ pos,
                        int* __restrict__ bsum, int n) {
    __shared__ int tmp[SCANB];
    int t = threadIdx.x, i = blockIdx.x * SCANB + t;
    int v = (i < n) ? deg[i] : 0;
    tmp[t] = v; __syncthreads();
    for (int off = 1; off < SCANB; off <<= 1) {
        int x = (t >= off) ? tmp[t - off] : 0;
        __syncthreads();
        tmp[t] += x;
        __syncthreads();
    }
    if (i < n) pos[i] = tmp[t] - v;           // exclusive within block
    if (t == SCANB - 1) bsum[blockIdx.x] = tmp[t];
}
__global__ void k_scan2(int* __restrict__ bsum, int nb) {
    __shared__ int tmp[512];
    int t = threadIdx.x;
    int v = (t < nb) ? bsum[t] : 0;
    tmp[t] = v; __syncthreads();
    for (int off = 1; off < 512; off <<= 1) {
        int x = (t >= off) ? tmp[t - off] : 0;
        __syncthreads();
        tmp[t] += x;
        __syncthreads();
    }
    if (t < nb) bsum[t] = tmp[t] - v;         // exclusive block offsets
}
__global__ void k_scan3(int* __restrict__ pos, const int* __restrict__ bsum, int n) {
    int i = blockIdx.x * blockDim.x + threadIdx.x;
    if (i < n) pos[i] += bsum[blockIdx.x];
}
// scatter src values into CSR order; pos[d] ends at segment END
__global__ void k_fill(const int* __restrict__ src, const int* __restrict__ dst,
                       int* __restrict__ pos, int* __restrict__ esrc) {
    int e = blockIdx.x * blockDim.x + threadIdx.x;
    if (e < EE) {
        int p = atomicAdd(&pos[dst[e]], 1);
        esrc[p] = src[e];
    }
}

// ---------------- dense layers ----------------
// h[N,128] = x[N,165] @ W[165,128] + b   (fp32 out)
__global__ void k_linear_in(fpp x, fpp W, fpp b, float* __restrict__ h, int n) {
    __shared__ float xs[RROWS][IN_DIM];
    int row0 = blockIdx.x * RROWS;
    int col = threadIdx.x;  // 0..127
    for (int r = 0; r < RROWS; r++) {
        int row = row0 + r;
        if (row < n)
            for (int i = col; i < IN_DIM; i += 128)
                xs[r][i] = x[(size_t)row * IN_DIM + i];
    }
    __syncthreads();
    float bb = b[col];
    float acc[RROWS];
    for (int r = 0; r < RROWS; r++) acc[r] = bb;
    for (int k = 0; k < IN_DIM; k++) {
        float w = W[k * HID + col];
        for (int r = 0; r < RROWS; r++) acc[r] += xs[r][k] * w;
    }
    for (int r = 0; r < RROWS; r++) {
        int row = row0 + r;
        if (row < n) h[(size_t)row * HID + col] = acc[r];
    }
}

// q,k,v = h @ {Wq,Wk,Wv} + bias   (bf16 out)
__global__ void k_qkv(const float* __restrict__ h, fpp Wq, fpp bq, fpp Wk, fpp bk,
                      fpp Wv, fpp bv, bf16* __restrict__ qb, bf16* __restrict__ kb,
                      bf16* __restrict__ vb, int n) {
    __shared__ float hs[RROWS][HID];
    int row0 = blockIdx.x * RROWS;
    int col = threadIdx.x;
    for (int r = 0; r < RROWS; r++) {
        int row = row0 + r;
        if (row < n) hs[r][col] = h[(size_t)row * HID + col];
    }
    __syncthreads();
    float aq[RROWS], ak[RROWS], av[RROWS];
    float bq_ = bq[col], bk_ = bk[col], bv_ = bv[col];
    for (int r = 0; r < RROWS; r++) { aq[r] = bq_; ak[r] = bk_; av[r] = bv_; }
    for (int t = 0; t < HID; t++) {
        float wq = Wq[t * HID + col];
        float wk = Wk[t * HID + col];
        float wv = Wv[t * HID + col];
        for (int r = 0; r < RROWS; r++) {
            float hv = hs[r][t];
            aq[r] += hv * wq; ak[r] += hv * wk; av[r] += hv * wv;
        }
    }
    for (int r = 0; r < RROWS; r++) {
        int row = row0 + r;
        if (row < n) {
            size_t o = (size_t)row * HID + col;
            qb[o] = __float2bfloat16(aq[r]);
            kb[o] = __float2bfloat16(ak[r]);
            vb[o] = __float2bfloat16(av[r]);
        }
    }
}

// agg = h @ Ws + bs  (bf16 out)
__global__ void k_skip(const float* __restrict__ h, fpp Ws, fpp bs,
                       bf16* __restrict__ agg, int n) {
    __shared__ float hs[RROWS][HID];
    int row0 = blockIdx.x * RROWS;
    int col = threadIdx.x;
    for (int r = 0; r < RROWS; r++) {
        int row = row0 + r;
        if (row < n) hs[r][col] = h[(size_t)row * HID + col];
    }
    __syncthreads();
    float bb = bs[col];
    float acc[RROWS];
    for (int r = 0; r < RROWS; r++) acc[r] = bb;
    for (int t = 0; t < HID; t++) {
        float w = Ws[t * HID + col];
        for (int r = 0; r < RROWS; r++) acc[r] += hs[r][t] * w;
    }
    for (int r = 0; r < RROWS; r++) {
        int row = row0 + r;
        if (row < n) agg[(size_t)row * HID + col] = __float2bfloat16(acc[r]);
    }
}

// ---------------- fused per-node attention aggregation ----------------
// one wave per dst node; lane l holds cols {2l,2l+1}; head = l>>3 (8 lanes/head)
__global__ void k_aggregate(const bf16* __restrict__ qb, const bf16* __restrict__ kb,
                            const bf16* __restrict__ vb, const int* __restrict__ pos,
                            const int* __restrict__ deg, const int* __restrict__ esrc,
                            bf16* __restrict__ agg) {
    int wid = (blockIdx.x * blockDim.x + threadIdx.x) >> 6;
    if (wid >= NN) return;
    int lane = threadIdx.x & 63;
    int d = wid;
    unsigned qu = ((const unsigned*)(qb + (size_t)d * HID))[lane];
    float q0 = bflo(qu) * 0.25f, q1 = bfhi(qu) * 0.25f;  // fold 1/sqrt(D)
    int cnt = deg[d];
    int start = pos[d] - cnt;  // pos holds segment end after k_fill
    float m = -INFINITY, L = 0.f, o0 = 0.f, o1 = 0.f;
    for (int j = 0; j < cnt; j++) {
        int s = esrc[start + j];
        unsigned ku = ((const unsigned*)(kb + (size_t)s * HID))[lane];
        float t = q0 * bflo(ku) + q1 * bfhi(ku);
        t += __shfl_xor(t, 1, 64);
        t += __shfl_xor(t, 2, 64);
        t += __shfl_xor(t, 4, 64);  // alpha, uniform within 8-lane head group
        float nm = fmaxf(m, t);
        float corr = expf(m - nm);  // first iter: exp(-inf)=0
        float p = expf(t - nm);
        unsigned vu = ((const unsigned*)(vb + (size_t)s * HID))[lane];
        L = L * corr + p;
        o0 = o0 * corr + p * bflo(vu);
        o1 = o1 * corr + p * bfhi(vu);
        m = nm;
    }
    float inv = 1.f / (L + 1e-16f);
    unsigned au = ((const unsigned*)(agg + (size_t)d * HID))[lane];
    float a0 = bflo(au) + o0 * inv;
    float a1 = bfhi(au) + o1 * inv;
    unsigned outw = ((unsigned)bfbits(a1) << 16) | bfbits(a0);
    ((unsigned*)(agg + (size_t)d * HID))[lane] = outw;
}

// h = layer_norm(h + agg) * g + b   (in place, one wave per row; lane l: cols 2l,2l+1)
__global__ void k_add_ln(float* __restrict__ h, const bf16* __restrict__ agg,
                         fpp g, fpp b) {
    int row = blockIdx.x;
    int l = threadIdx.x;  // 0..63
    float2 hv = ((float2*)(h + (size_t)row * HID))[l];
    unsigned au = ((const unsigned*)(agg + (size_t)row * HID))[l];
    float v0 = hv.x + bflo(au);
    float v1 = hv.y + bfhi(au);
    float s = v0 + v1, s2 = v0 * v0 + v1 * v1;
    for (int off = 32; off; off >>= 1) {
        s += __shfl_xor(s, off, 64);
        s2 += __shfl_xor(s2, off, 64);
    }
    float mn = s * (1.f / HID);
    float var = s2 * (1.f / HID) - mn * mn;
    float inv = rsqrtf(var + 1e-5f);
    float2 gv = ((const float2*)g)[l];
    float2 bv = ((const float2*)b)[l];
    float2 o;
    o.x = (v0 - mn) * inv * gv.x + bv.x;
    o.y = (v1 - mn) * inv * gv.y + bv.y;
    ((float2*)(h + (size_t)row * HID))[l] = o;
}

// out = relu(h@Wc1+bc1) @ Wc2 + bc2, one wave per row (fp32 out)
__global__ void k_classifier(const float* __restrict__ h, fpp Wc1, fpp bc1, fpp Wc2,
                             fpp bc2, float* __restrict__ out) {
    __shared__ float hs[HID];
    int row = blockIdx.x;
    int t = threadIdx.x;  // 0..63
    hs[t] = h[(size_t)row * HID + t];
    hs[t + 64] = h[(size_t)row * HID + t + 64];
    __syncthreads();
    float acc = bc1[t];
    for (int k = 0; k < HID; k++) acc += hs[k] * Wc1[k * C1 + t];
    acc = fmaxf(acc, 0.f);
    float p0 = acc * Wc2[t * NC + 0];
    float p1 = acc * Wc2[t * NC + 1];
    for (int off = 32; off; off >>= 1) {
        p0 += __shfl_xor(p0, off, 64);
        p1 += __shfl_xor(p1, off, 64);
    }
    if (t == 0) {
        out[(size_t)row * NC + 0] = p0 + bc2[0];
        out[(size_t)row * NC + 1] = p1 + bc2[1];
    }
}

extern "C" void kernel_launch(void* const* d_in, const int* in_sizes, int n_in,
                              void* d_out, int out_size, void* d_ws, size_t ws_size,
                              hipStream_t stream) {
    fpp x = (fpp)d_in[0];
    const int* ei = (const int*)d_in[1];
    const int* src = ei;
    const int* dst = ei + EE;
    fpp W_in = (fpp)d_in[2];  fpp b_in = (fpp)d_in[3];
    fpp Wq1 = (fpp)d_in[4];   fpp bq1 = (fpp)d_in[5];
    fpp Wk1 = (fpp)d_in[6];   fpp bk1 = (fpp)d_in[7];
    fpp Wv1 = (fpp)d_in[8];   fpp bv1 = (fpp)d_in[9];
    fpp Ws1 = (fpp)d_in[10];  fpp bs1 = (fpp)d_in[11];
    fpp g1 = (fpp)d_in[12];   fpp be1 = (fpp)d_in[13];
    fpp Wq2 = (fpp)d_in[14];  fpp bq2 = (fpp)d_in[15];
    fpp Wk2 = (fpp)d_in[16];  fpp bk2 = (fpp)d_in[17];
    fpp Wv2 = (fpp)d_in[18];  fpp bv2 = (fpp)d_in[19];
    fpp Ws2 = (fpp)d_in[20];  fpp bs2 = (fpp)d_in[21];
    fpp g2 = (fpp)d_in[22];   fpp be2 = (fpp)d_in[23];
    fpp Wc1 = (fpp)d_in[24];  fpp bc1 = (fpp)d_in[25];
    fpp Wc2 = (fpp)d_in[26];  fpp bc2 = (fpp)d_in[27];
    float* out = (float*)d_out;

    // workspace layout (~156 MB)
    char* p = (char*)d_ws;
    float* h = (float*)p;            p += (size_t)NN * HID * 4;   // 51.2 MB
    bf16* agg = (bf16*)p;            p += (size_t)NN * HID * 2;   // 25.6 MB
    bf16* qb = (bf16*)p;             p += (size_t)NN * HID * 2;   // 25.6 MB
    bf16* kb = (bf16*)p;             p += (size_t)NN * HID * 2;   // 25.6 MB
    bf16* vb = (bf16*)p;             p += (size_t)NN * HID * 2;   // 25.6 MB
    int* deg = (int*)p;              p += (size_t)NN * 4;         // 0.4 MB
    int* pos = (int*)p;              p += (size_t)NN * 4;         // 0.4 MB
    int* esrc = (int*)p;             p += (size_t)EE * 4;         // 1.6 MB
    int* bsum = (int*)p;             p += 512 * 4;

    const int nbd = (NN + RROWS - 1) / RROWS;
    const int nE = (EE + 255) / 256;
    const int nNn = (NN + 255) / 256;

    // CSR build (edge structure shared by both layers)
    k_deg_zero<<<nNn, 256, 0, stream>>>(deg);
    k_hist<<<nE, 256, 0, stream>>>(dst, deg);
    k_scan1<<<NBLK, SCANB, 0, stream>>>(deg, pos, bsum, NN);
    k_scan2<<<1, 512, 0, stream>>>(bsum, NBLK);
    k_scan3<<<NBLK, SCANB, 0, stream>>>(pos, bsum, NN);
    k_fill<<<nE, 256, 0, stream>>>(src, dst, pos, esrc);

    k_linear_in<<<nbd, 128, 0, stream>>>(x, W_in, b_in, h, NN);

    for (int layer = 0; layer < 2; layer++) {
        fpp Wq = layer ? Wq2 : Wq1, bq = layer ? bq2 : bq1;
        fpp Wk = layer ? Wk2 : Wk1, bk = layer ? bk2 : bk1;
        fpp Wv = layer ? Wv2 : Wv1, bv = layer ? bv2 : bv1;
        fpp Wss = layer ? Ws2 : Ws1, bss = layer ? bs2 : bs1;
        fpp g = layer ? g2 : g1, be = layer ? be2 : be1;

        k_qkv<<<nbd, 128, 0, stream>>>(h, Wq, bq, Wk, bk, Wv, bv, qb, kb, vb, NN);
        k_skip<<<nbd, 128, 0, stream>>>(h, Wss, bss, agg, NN);
        k_aggregate<<<(NN * 64 + 255) / 256, 256, 0, stream>>>(qb, kb, vb, pos, deg, esrc, agg);
        k_add_ln<<<NN, 64, 0, stream>>>(h, agg, g, be);
    }

    k_classifier<<<NN, 64, 0, stream>>>(h, Wc1, bc1, Wc2, bc2, out);
}

// Round 5
// 528.786 us; speedup vs baseline: 2.6413x; 2.1342x over previous
//
#include <hip/hip_runtime.h>
#include <hip/hip_bf16.h>

#define NN 100000
#define EE 400000
#define IN_DIM 165
#define KPAD 192
#define HID 128
#define C1 64
#define NC 2
#define SCANB 256
#define NBLK 391   // ceil(100000/256)
#define NBD2 782   // ceil(100000/128)

typedef const float* fpp;
typedef __hip_bfloat16 bf16;
typedef __attribute__((ext_vector_type(8))) short s16x8;
typedef __attribute__((ext_vector_type(4))) float f32x4;

__device__ __forceinline__ float bflo(unsigned u) { return __uint_as_float(u << 16); }
__device__ __forceinline__ float bfhi(unsigned u) { return __uint_as_float(u & 0xFFFF0000u); }
__device__ __forceinline__ unsigned short bfbits(float f) {
    bf16 h = __float2bfloat16(f);
    return *reinterpret_cast<unsigned short*>(&h);
}

// ---------------- weight conversion / packing (bf16, transposed) ----------------
// regions: [0,24576) winpack[128][192]; [24576,155648) wpack 8x[128][128]; [155648,163840) wc1t[64][128]
__global__ void k_cvt_weights(fpp W_in, fpp Wq1, fpp Wk1, fpp Wv1, fpp Ws1,
                              fpp Wq2, fpp Wk2, fpp Wv2, fpp Ws2, fpp Wc1,
                              unsigned short* __restrict__ winpack,
                              unsigned short* __restrict__ wpack,
                              unsigned short* __restrict__ wc1t) {
    int idx = blockIdx.x * blockDim.x + threadIdx.x;
    if (idx < 24576) {
        int n = idx / KPAD, k = idx % KPAD;
        float v = (k < IN_DIM) ? W_in[k * HID + n] : 0.f;
        winpack[idx] = bfbits(v);
    } else if (idx < 155648) {
        int local = idx - 24576;
        int j = local >> 14;             // 0..7: layer*4 + tgt
        int l14 = local & 16383;
        int n = l14 >> 7, k = l14 & 127;
        const float* src;
        switch (j) {
            case 0: src = Wq1; break; case 1: src = Wk1; break;
            case 2: src = Wv1; break; case 3: src = Ws1; break;
            case 4: src = Wq2; break; case 5: src = Wk2; break;
            case 6: src = Wv2; break; default: src = Ws2; break;
        }
        wpack[local] = bfbits(src[k * HID + n]);
    } else {
        int local = idx - 155648;
        int n = local >> 7, k = local & 127;
        wc1t[local] = bfbits(Wc1[k * C1 + n]);
    }
}

// x[N,165] fp32 -> xb[N,192] bf16 (zero-padded)
__global__ void k_cvt_x(fpp x, unsigned short* __restrict__ xb) {
    int i = blockIdx.x * blockDim.x + threadIdx.x;  // over N*24
    int row = i / 24, c = i % 24;
    s16x8 us;
#pragma unroll
    for (int j = 0; j < 8; j++) {
        int col = c * 8 + j;
        float v = (col < IN_DIM) ? x[(size_t)row * IN_DIM + col] : 0.f;
        us[j] = (short)bfbits(v);
    }
    *(s16x8*)(xb + (size_t)row * KPAD + c * 8) = us;
}

// ---------------- CSR build ----------------
__global__ void k_deg_zero(int* __restrict__ deg) {
    int i = blockIdx.x * blockDim.x + threadIdx.x;
    if (i < NN) deg[i] = 0;
}
__global__ void k_hist(const int* __restrict__ dst, int* __restrict__ deg) {
    int e = blockIdx.x * blockDim.x + threadIdx.x;
    if (e < EE) atomicAdd(&deg[dst[e]], 1);
}
__global__ void k_scan1(const int* __restrict__ deg, int* __restrict__ pos,
                        int* __restrict__ bsum, int n) {
    __shared__ int tmp[SCANB];
    int t = threadIdx.x, i = blockIdx.x * SCANB + t;
    int v = (i < n) ? deg[i] : 0;
    tmp[t] = v; __syncthreads();
    for (int off = 1; off < SCANB; off <<= 1) {
        int x = (t >= off) ? tmp[t - off] : 0;
        __syncthreads();
        tmp[t] += x;
        __syncthreads();
    }
    if (i < n) pos[i] = tmp[t] - v;
    if (t == SCANB - 1) bsum[blockIdx.x] = tmp[t];
}
__global__ void k_scan2(int* __restrict__ bsum, int nb) {
    __shared__ int tmp[512];
    int t = threadIdx.x;
    int v = (t < nb) ? bsum[t] : 0;
    tmp[t] = v; __syncthreads();
    for (int off = 1; off < 512; off <<= 1) {
        int x = (t >= off) ? tmp[t - off] : 0;
        __syncthreads();
        tmp[t] += x;
        __syncthreads();
    }
    if (t < nb) bsum[t] = tmp[t] - v;
}
__global__ void k_scan3(int* __restrict__ pos, const int* __restrict__ bsum, int n) {
    int i = blockIdx.x * blockDim.x + threadIdx.x;
    if (i < n) pos[i] += bsum[blockIdx.x];
}
__global__ void k_fill(const int* __restrict__ src, const int* __restrict__ dst,
                       int* __restrict__ pos, int* __restrict__ esrc) {
    int e = blockIdx.x * blockDim.x + threadIdx.x;
    if (e < EE) {
        int p = atomicAdd(&pos[dst[e]], 1);
        esrc[p] = src[e];
    }
}

// ---------------- MFMA input projection: h = xb @ winpack^T + b_in (fp32 out) ----------------
__global__ __launch_bounds__(256) void k_dense_in(const unsigned short* __restrict__ xb,
                                                  const unsigned short* __restrict__ winpack,
                                                  fpp b_in, float* __restrict__ h) {
    __shared__ unsigned short As[128 * 72];
    __shared__ unsigned short Ws[128 * 72];
    int row0 = blockIdx.x * 128;
    int t = threadIdx.x, lane = t & 63, w = t >> 6;
    int quad = lane >> 4, l16 = lane & 15;
    int m_off = (w >> 1) * 64, n_off = (w & 1) * 64;

    f32x4 acc[4][4];
    float bias_v[4];
#pragma unroll
    for (int ni = 0; ni < 4; ni++) bias_v[ni] = b_in[n_off + ni * 16 + l16];
#pragma unroll
    for (int mi = 0; mi < 4; mi++)
#pragma unroll
        for (int ni = 0; ni < 4; ni++)
            acc[mi][ni] = (f32x4){bias_v[ni], bias_v[ni], bias_v[ni], bias_v[ni]};

    for (int kc = 0; kc < 3; kc++) {
        __syncthreads();
        // stage A chunk [128][64] and W chunk [128][64]
        for (int i = 0; i < 4; i++) {
            int g = t + i * 256;
            int r = g >> 3, c = g & 7;
            int rg = min(row0 + r, NN - 1);
            *(s16x8*)(As + r * 72 + c * 8) =
                *(const s16x8*)(xb + (size_t)rg * KPAD + kc * 64 + c * 8);
            *(s16x8*)(Ws + r * 72 + c * 8) =
                *(const s16x8*)(winpack + r * KPAD + kc * 64 + c * 8);
        }
        __syncthreads();
#pragma unroll
        for (int ks = 0; ks < 2; ks++) {
            int k0 = ks * 32;
            s16x8 a[4], b[4];
#pragma unroll
            for (int mi = 0; mi < 4; mi++)
                a[mi] = *(const s16x8*)(As + (m_off + mi * 16 + l16) * 72 + k0 + quad * 8);
#pragma unroll
            for (int ni = 0; ni < 4; ni++)
                b[ni] = *(const s16x8*)(Ws + (n_off + ni * 16 + l16) * 72 + k0 + quad * 8);
#pragma unroll
            for (int mi = 0; mi < 4; mi++)
#pragma unroll
                for (int ni = 0; ni < 4; ni++)
                    acc[mi][ni] = __builtin_amdgcn_mfma_f32_16x16x32_bf16(
                        a[mi], b[ni], acc[mi][ni], 0, 0, 0);
        }
    }
    // direct fp32 stores: row = m_off+mi*16+quad*4+r, col = n_off+ni*16+l16
#pragma unroll
    for (int mi = 0; mi < 4; mi++)
#pragma unroll
        for (int ni = 0; ni < 4; ni++)
#pragma unroll
            for (int r = 0; r < 4; r++) {
                int m = row0 + m_off + mi * 16 + quad * 4 + r;
                if (m < NN)
                    h[(size_t)m * HID + n_off + ni * 16 + l16] = acc[mi][ni][r];
            }
}

// ---------------- MFMA fused q/k/v/skip: [N,512] = h @ wpack^T, bf16 out ----------------
__global__ __launch_bounds__(256) void k_dense4(const float* __restrict__ h,
                                                const unsigned short* __restrict__ wpackL,
                                                fpp bq, fpp bk, fpp bv, fpp bs,
                                                bf16* __restrict__ qb, bf16* __restrict__ kb,
                                                bf16* __restrict__ vb, bf16* __restrict__ agg) {
    __shared__ unsigned short As[128 * 136];
    __shared__ unsigned short Ws[128 * 136];
    int row0 = blockIdx.x * 128;
    int t = threadIdx.x, lane = t & 63, w = t >> 6;
    int quad = lane >> 4, l16 = lane & 15;
    int m_off = (w >> 1) * 64, n_off = (w & 1) * 64;

    // stage A (h fp32 -> bf16), [128][128] padded to 136
    for (int i = 0; i < 8; i++) {
        int g = t + i * 256;
        int r = g >> 4, c = g & 15;
        int rg = min(row0 + r, NN - 1);
        float4 f0 = *(const float4*)(h + (size_t)rg * HID + c * 8);
        float4 f1 = *(const float4*)(h + (size_t)rg * HID + c * 8 + 4);
        s16x8 us;
        us[0] = (short)bfbits(f0.x); us[1] = (short)bfbits(f0.y);
        us[2] = (short)bfbits(f0.z); us[3] = (short)bfbits(f0.w);
        us[4] = (short)bfbits(f1.x); us[5] = (short)bfbits(f1.y);
        us[6] = (short)bfbits(f1.z); us[7] = (short)bfbits(f1.w);
        *(s16x8*)(As + r * 136 + c * 8) = us;
    }
    __syncthreads();

    // hoist a-fragments (reused across all 4 output chunks)
    s16x8 afr[4][4];  // [ks][mi]
#pragma unroll
    for (int ks = 0; ks < 4; ks++)
#pragma unroll
        for (int mi = 0; mi < 4; mi++)
            afr[ks][mi] = *(const s16x8*)(As + (m_off + mi * 16 + l16) * 136 + ks * 32 + quad * 8);

    for (int nc = 0; nc < 4; nc++) {
        const float* bp; bf16* tp;
        if (nc == 0)      { bp = bq; tp = qb; }
        else if (nc == 1) { bp = bk; tp = kb; }
        else if (nc == 2) { bp = bv; tp = vb; }
        else              { bp = bs; tp = agg; }

        __syncthreads();  // prior-iteration Cs consumers done (Cs aliases Ws)
        // stage W chunk [128][128]
        for (int i = 0; i < 8; i++) {
            int g = t + i * 256;
            int r = g >> 4, c = g & 15;
            *(s16x8*)(Ws + r * 136 + c * 8) =
                *(const s16x8*)(wpackL + nc * 16384 + r * HID + c * 8);
        }
        __syncthreads();

        f32x4 acc[4][4];
        float bias_v[4];
#pragma unroll
        for (int ni = 0; ni < 4; ni++) bias_v[ni] = bp[n_off + ni * 16 + l16];
#pragma unroll
        for (int mi = 0; mi < 4; mi++)
#pragma unroll
            for (int ni = 0; ni < 4; ni++)
                acc[mi][ni] = (f32x4){bias_v[ni], bias_v[ni], bias_v[ni], bias_v[ni]};

#pragma unroll
        for (int ks = 0; ks < 4; ks++) {
            s16x8 b[4];
#pragma unroll
            for (int ni = 0; ni < 4; ni++)
                b[ni] = *(const s16x8*)(Ws + (n_off + ni * 16 + l16) * 136 + ks * 32 + quad * 8);
#pragma unroll
            for (int mi = 0; mi < 4; mi++)
#pragma unroll
                for (int ni = 0; ni < 4; ni++)
                    acc[mi][ni] = __builtin_amdgcn_mfma_f32_16x16x32_bf16(
                        afr[ks][mi], b[ni], acc[mi][ni], 0, 0, 0);
        }
        __syncthreads();  // all waves done reading Ws

        // bounce C through LDS (bf16) for coalesced stores
        unsigned short* Cs = Ws;
#pragma unroll
        for (int mi = 0; mi < 4; mi++)
#pragma unroll
            for (int ni = 0; ni < 4; ni++)
#pragma unroll
                for (int r = 0; r < 4; r++)
                    Cs[(m_off + mi * 16 + quad * 4 + r) * 136 + n_off + ni * 16 + l16] =
                        bfbits(acc[mi][ni][r]);
        __syncthreads();
        for (int i = 0; i < 8; i++) {
            int g = t + i * 256;
            int r = g >> 4, c = g & 15;
            if (row0 + r < NN)
                *(s16x8*)((unsigned short*)tp + (size_t)(row0 + r) * HID + c * 8) =
                    *(const s16x8*)(Cs + r * 136 + c * 8);
        }
    }
}

// ---------------- fused per-node attention aggregation ----------------
__global__ void k_aggregate(const bf16* __restrict__ qb, const bf16* __restrict__ kb,
                            const bf16* __restrict__ vb, const int* __restrict__ pos,
                            const int* __restrict__ deg, const int* __restrict__ esrc,
                            bf16* __restrict__ agg) {
    int wid = (blockIdx.x * blockDim.x + threadIdx.x) >> 6;
    if (wid >= NN) return;
    int lane = threadIdx.x & 63;
    int d = wid;
    unsigned qu = ((const unsigned*)(qb + (size_t)d * HID))[lane];
    float q0 = bflo(qu) * 0.25f, q1 = bfhi(qu) * 0.25f;  // fold 1/sqrt(D)
    int cnt = deg[d];
    int start = pos[d] - cnt;
    float m = -INFINITY, L = 0.f, o0 = 0.f, o1 = 0.f;
    for (int j = 0; j < cnt; j++) {
        int s = esrc[start + j];
        unsigned ku = ((const unsigned*)(kb + (size_t)s * HID))[lane];
        float tt = q0 * bflo(ku) + q1 * bfhi(ku);
        tt += __shfl_xor(tt, 1, 64);
        tt += __shfl_xor(tt, 2, 64);
        tt += __shfl_xor(tt, 4, 64);
        float nm = fmaxf(m, tt);
        float corr = expf(m - nm);
        float p = expf(tt - nm);
        unsigned vu = ((const unsigned*)(vb + (size_t)s * HID))[lane];
        L = L * corr + p;
        o0 = o0 * corr + p * bflo(vu);
        o1 = o1 * corr + p * bfhi(vu);
        m = nm;
    }
    float inv = 1.f / (L + 1e-16f);
    unsigned au = ((const unsigned*)(agg + (size_t)d * HID))[lane];
    float a0 = bflo(au) + o0 * inv;
    float a1 = bfhi(au) + o1 * inv;
    unsigned outw = ((unsigned)bfbits(a1) << 16) | bfbits(a0);
    ((unsigned*)(agg + (size_t)d * HID))[lane] = outw;
}

// h = layer_norm(h + agg) * g + b   (in place)
__global__ void k_add_ln(float* __restrict__ h, const bf16* __restrict__ agg,
                         fpp g, fpp b) {
    int row = blockIdx.x;
    int l = threadIdx.x;
    float2 hv = ((float2*)(h + (size_t)row * HID))[l];
    unsigned au = ((const unsigned*)(agg + (size_t)row * HID))[l];
    float v0 = hv.x + bflo(au);
    float v1 = hv.y + bfhi(au);
    float s = v0 + v1, s2 = v0 * v0 + v1 * v1;
    for (int off = 32; off; off >>= 1) {
        s += __shfl_xor(s, off, 64);
        s2 += __shfl_xor(s2, off, 64);
    }
    float mn = s * (1.f / HID);
    float var = s2 * (1.f / HID) - mn * mn;
    float inv = rsqrtf(var + 1e-5f);
    float2 gv = ((const float2*)g)[l];
    float2 bv = ((const float2*)b)[l];
    float2 o;
    o.x = (v0 - mn) * inv * gv.x + bv.x;
    o.y = (v1 - mn) * inv * gv.y + bv.y;
    ((float2*)(h + (size_t)row * HID))[l] = o;
}

// ---------------- MFMA classifier: out = relu(h@Wc1+bc1) @ Wc2 + bc2 ----------------
__global__ __launch_bounds__(256) void k_classifier(const float* __restrict__ h,
                                                    const unsigned short* __restrict__ wc1t,
                                                    fpp bc1, fpp Wc2, fpp bc2,
                                                    float* __restrict__ out) {
    __shared__ unsigned short As[128 * 136];
    __shared__ unsigned short Ws[64 * 136];
    int row0 = blockIdx.x * 128;
    int t = threadIdx.x, lane = t & 63, w = t >> 6;
    int quad = lane >> 4, l16 = lane & 15;
    int m_off = w * 32;

    for (int i = 0; i < 8; i++) {
        int g = t + i * 256;
        int r = g >> 4, c = g & 15;
        int rg = min(row0 + r, NN - 1);
        float4 f0 = *(const float4*)(h + (size_t)rg * HID + c * 8);
        float4 f1 = *(const float4*)(h + (size_t)rg * HID + c * 8 + 4);
        s16x8 us;
        us[0] = (short)bfbits(f0.x); us[1] = (short)bfbits(f0.y);
        us[2] = (short)bfbits(f0.z); us[3] = (short)bfbits(f0.w);
        us[4] = (short)bfbits(f1.x); us[5] = (short)bfbits(f1.y);
        us[6] = (short)bfbits(f1.z); us[7] = (short)bfbits(f1.w);
        *(s16x8*)(As + r * 136 + c * 8) = us;
    }
    for (int i = 0; i < 4; i++) {
        int g = t + i * 256;
        int r = g >> 4, c = g & 15;
        *(s16x8*)(Ws + r * 136 + c * 8) = *(const s16x8*)(wc1t + r * HID + c * 8);
    }
    __syncthreads();

    f32x4 acc[2][4];
    float bias_v[4];
#pragma unroll
    for (int ni = 0; ni < 4; ni++) bias_v[ni] = bc1[ni * 16 + l16];
#pragma unroll
    for (int mi = 0; mi < 2; mi++)
#pragma unroll
        for (int ni = 0; ni < 4; ni++)
            acc[mi][ni] = (f32x4){bias_v[ni], bias_v[ni], bias_v[ni], bias_v[ni]};

#pragma unroll
    for (int ks = 0; ks < 4; ks++) {
        s16x8 a[2], b[4];
#pragma unroll
        for (int mi = 0; mi < 2; mi++)
            a[mi] = *(const s16x8*)(As + (m_off + mi * 16 + l16) * 136 + ks * 32 + quad * 8);
#pragma unroll
        for (int ni = 0; ni < 4; ni++)
            b[ni] = *(const s16x8*)(Ws + (ni * 16 + l16) * 136 + ks * 32 + quad * 8);
#pragma unroll
        for (int mi = 0; mi < 2; mi++)
#pragma unroll
            for (int ni = 0; ni < 4; ni++)
                acc[mi][ni] = __builtin_amdgcn_mfma_f32_16x16x32_bf16(
                    a[mi], b[ni], acc[mi][ni], 0, 0, 0);
    }
    __syncthreads();  // done reading As; reuse as fp32 Cs[128][68]
    float* Cs = (float*)As;
#pragma unroll
    for (int mi = 0; mi < 2; mi++)
#pragma unroll
        for (int ni = 0; ni < 4; ni++)
#pragma unroll
            for (int r = 0; r < 4; r++)
                Cs[(m_off + mi * 16 + quad * 4 + r) * 68 + ni * 16 + l16] =
                    fmaxf(acc[mi][ni][r], 0.f);
    __syncthreads();

    int row = t >> 1, half = t & 1;
    float p0 = 0.f, p1 = 0.f;
    for (int c = half * 32; c < half * 32 + 32; c++) {
        float v = Cs[row * 68 + c];
        p0 += v * Wc2[c * NC + 0];
        p1 += v * Wc2[c * NC + 1];
    }
    p0 += __shfl_xor(p0, 1, 64);
    p1 += __shfl_xor(p1, 1, 64);
    if (half == 0 && row0 + row < NN) {
        out[(size_t)(row0 + row) * NC + 0] = p0 + bc2[0];
        out[(size_t)(row0 + row) * NC + 1] = p1 + bc2[1];
    }
}

extern "C" void kernel_launch(void* const* d_in, const int* in_sizes, int n_in,
                              void* d_out, int out_size, void* d_ws, size_t ws_size,
                              hipStream_t stream) {
    fpp x = (fpp)d_in[0];
    const int* ei = (const int*)d_in[1];
    const int* src = ei;
    const int* dst = ei + EE;
    fpp W_in = (fpp)d_in[2];  fpp b_in = (fpp)d_in[3];
    fpp Wq1 = (fpp)d_in[4];   fpp bq1 = (fpp)d_in[5];
    fpp Wk1 = (fpp)d_in[6];   fpp bk1 = (fpp)d_in[7];
    fpp Wv1 = (fpp)d_in[8];   fpp bv1 = (fpp)d_in[9];
    fpp Ws1 = (fpp)d_in[10];  fpp bs1 = (fpp)d_in[11];
    fpp g1 = (fpp)d_in[12];   fpp be1 = (fpp)d_in[13];
    fpp Wq2 = (fpp)d_in[14];  fpp bq2 = (fpp)d_in[15];
    fpp Wk2 = (fpp)d_in[16];  fpp bk2 = (fpp)d_in[17];
    fpp Wv2 = (fpp)d_in[18];  fpp bv2 = (fpp)d_in[19];
    fpp Ws2 = (fpp)d_in[20];  fpp bs2 = (fpp)d_in[21];
    fpp g2 = (fpp)d_in[22];   fpp be2 = (fpp)d_in[23];
    fpp Wc1 = (fpp)d_in[24];  fpp bc1 = (fpp)d_in[25];
    fpp Wc2 = (fpp)d_in[26];  fpp bc2 = (fpp)d_in[27];
    float* out = (float*)d_out;

    // workspace layout (~156.5 MB)
    char* p = (char*)d_ws;
    float* h = (float*)p;            p += (size_t)NN * HID * 4;   // 51.2 MB
    bf16* agg = (bf16*)p;            p += (size_t)NN * HID * 2;   // 25.6 MB
    bf16* qb = (bf16*)p;             p += (size_t)NN * HID * 2;   // 25.6 MB
    bf16* kb = (bf16*)p;             p += (size_t)NN * HID * 2;   // 25.6 MB
    bf16* vb = (bf16*)p;             p += (size_t)NN * HID * 2;   // 25.6 MB
    int* deg = (int*)p;              p += (size_t)NN * 4;
    int* pos = (int*)p;              p += (size_t)NN * 4;
    int* esrc = (int*)p;             p += (size_t)EE * 4;
    int* bsum = (int*)p;             p += 512 * 4;
    unsigned short* winpack = (unsigned short*)p;  p += 24576 * 2;
    unsigned short* wpack = (unsigned short*)p;    p += 131072 * 2;
    unsigned short* wc1t = (unsigned short*)p;     p += 8192 * 2;
    // xb aliases qb+kb (dead until layer-1 k_dense4)
    unsigned short* xb = (unsigned short*)qb;      // N*192 bf16 = 38.4 MB <= 51.2

    const int nE = (EE + 255) / 256;
    const int nNn = (NN + 255) / 256;

    k_cvt_weights<<<640, 256, 0, stream>>>(W_in, Wq1, Wk1, Wv1, Ws1,
                                           Wq2, Wk2, Wv2, Ws2, Wc1,
                                           winpack, wpack, wc1t);
    k_cvt_x<<<9375, 256, 0, stream>>>(x, xb);

    // CSR build
    k_deg_zero<<<nNn, 256, 0, stream>>>(deg);
    k_hist<<<nE, 256, 0, stream>>>(dst, deg);
    k_scan1<<<NBLK, SCANB, 0, stream>>>(deg, pos, bsum, NN);
    k_scan2<<<1, 512, 0, stream>>>(bsum, NBLK);
    k_scan3<<<NBLK, SCANB, 0, stream>>>(pos, bsum, NN);
    k_fill<<<nE, 256, 0, stream>>>(src, dst, pos, esrc);

    k_dense_in<<<NBD2, 256, 0, stream>>>(xb, winpack, b_in, h);

    for (int layer = 0; layer < 2; layer++) {
        fpp bq = layer ? bq2 : bq1, bk = layer ? bk2 : bk1;
        fpp bv = layer ? bv2 : bv1, bs = layer ? bs2 : bs1;
        fpp g = layer ? g2 : g1, be = layer ? be2 : be1;
        const unsigned short* wpackL = wpack + (size_t)layer * 65536;

        k_dense4<<<NBD2, 256, 0, stream>>>(h, wpackL, bq, bk, bv, bs, qb, kb, vb, agg);
        k_aggregate<<<(NN * 64 + 255) / 256, 256, 0, stream>>>(qb, kb, vb, pos, deg, esrc, agg);
        k_add_ln<<<NN, 64, 0, stream>>>(h, agg, g, be);
    }

    k_classifier<<<NBD2, 256, 0, stream>>>(h, wc1t, bc1, Wc2, bc2, out);
}

// Round 6
// 448.896 us; speedup vs baseline: 3.1114x; 1.1780x over previous
//
#include <hip/hip_runtime.h>
#include <hip/hip_bf16.h>

#define NN 100000
#define EE 400000
#define IN_DIM 165
#define KPAD 192
#define HID 128
#define C1 64
#define NC 2
#define SCANB 256
#define NBLK 391   // ceil(100000/256)
#define NBD2 782   // ceil(100000/128)

typedef const float* fpp;
typedef __hip_bfloat16 bf16;
typedef __attribute__((ext_vector_type(8))) short s16x8;
typedef __attribute__((ext_vector_type(4))) float f32x4;

__device__ __forceinline__ float bflo(unsigned u) { return __uint_as_float(u << 16); }
__device__ __forceinline__ float bfhi(unsigned u) { return __uint_as_float(u & 0xFFFF0000u); }
__device__ __forceinline__ unsigned short bfbits(float f) {
    bf16 h = __float2bfloat16(f);
    return *reinterpret_cast<unsigned short*>(&h);
}

// ---------------- weight conversion / packing (bf16, transposed) ----------------
__global__ void k_cvt_weights(fpp W_in, fpp Wq1, fpp Wk1, fpp Wv1, fpp Ws1,
                              fpp Wq2, fpp Wk2, fpp Wv2, fpp Ws2, fpp Wc1,
                              unsigned short* __restrict__ winpack,
                              unsigned short* __restrict__ wpack,
                              unsigned short* __restrict__ wc1t) {
    int idx = blockIdx.x * blockDim.x + threadIdx.x;
    if (idx < 24576) {
        int n = idx / KPAD, k = idx % KPAD;
        float v = (k < IN_DIM) ? W_in[k * HID + n] : 0.f;
        winpack[idx] = bfbits(v);
    } else if (idx < 155648) {
        int local = idx - 24576;
        int j = local >> 14;
        int l14 = local & 16383;
        int n = l14 >> 7, k = l14 & 127;
        const float* src;
        switch (j) {
            case 0: src = Wq1; break; case 1: src = Wk1; break;
            case 2: src = Wv1; break; case 3: src = Ws1; break;
            case 4: src = Wq2; break; case 5: src = Wk2; break;
            case 6: src = Wv2; break; default: src = Ws2; break;
        }
        wpack[local] = bfbits(src[k * HID + n]);
    } else {
        int local = idx - 155648;
        int n = local >> 7, k = local & 127;
        wc1t[local] = bfbits(Wc1[k * C1 + n]);
    }
}

// x[N,165] fp32 -> xb[N,192] bf16 (zero-padded)
__global__ void k_cvt_x(fpp x, unsigned short* __restrict__ xb) {
    int i = blockIdx.x * blockDim.x + threadIdx.x;  // over N*24
    int row = i / 24, c = i % 24;
    s16x8 us;
#pragma unroll
    for (int j = 0; j < 8; j++) {
        int col = c * 8 + j;
        float v = (col < IN_DIM) ? x[(size_t)row * IN_DIM + col] : 0.f;
        us[j] = (short)bfbits(v);
    }
    *(s16x8*)(xb + (size_t)row * KPAD + c * 8) = us;
}

// ---------------- CSR build ----------------
__global__ void k_deg_zero(int* __restrict__ deg) {
    int i = blockIdx.x * blockDim.x + threadIdx.x;
    if (i < NN) deg[i] = 0;
}
__global__ void k_hist(const int* __restrict__ dst, int* __restrict__ deg) {
    int e = blockIdx.x * blockDim.x + threadIdx.x;
    if (e < EE) atomicAdd(&deg[dst[e]], 1);
}
__global__ void k_scan1(const int* __restrict__ deg, int* __restrict__ pos,
                        int* __restrict__ bsum, int n) {
    __shared__ int tmp[SCANB];
    int t = threadIdx.x, i = blockIdx.x * SCANB + t;
    int v = (i < n) ? deg[i] : 0;
    tmp[t] = v; __syncthreads();
    for (int off = 1; off < SCANB; off <<= 1) {
        int x = (t >= off) ? tmp[t - off] : 0;
        __syncthreads();
        tmp[t] += x;
        __syncthreads();
    }
    if (i < n) pos[i] = tmp[t] - v;
    if (t == SCANB - 1) bsum[blockIdx.x] = tmp[t];
}
__global__ void k_scan2(int* __restrict__ bsum, int nb) {
    __shared__ int tmp[512];
    int t = threadIdx.x;
    int v = (t < nb) ? bsum[t] : 0;
    tmp[t] = v; __syncthreads();
    for (int off = 1; off < 512; off <<= 1) {
        int x = (t >= off) ? tmp[t - off] : 0;
        __syncthreads();
        tmp[t] += x;
        __syncthreads();
    }
    if (t < nb) bsum[t] = tmp[t] - v;
}
__global__ void k_scan3(int* __restrict__ pos, const int* __restrict__ bsum, int n) {
    int i = blockIdx.x * blockDim.x + threadIdx.x;
    if (i < n) pos[i] += bsum[blockIdx.x];
}
__global__ void k_fill(const int* __restrict__ src, const int* __restrict__ dst,
                       int* __restrict__ pos, int* __restrict__ esrc) {
    int e = blockIdx.x * blockDim.x + threadIdx.x;
    if (e < EE) {
        int p = atomicAdd(&pos[dst[e]], 1);
        esrc[p] = src[e];
    }
}

// ---------------- MFMA input projection ----------------
__global__ __launch_bounds__(256) void k_dense_in(const unsigned short* __restrict__ xb,
                                                  const unsigned short* __restrict__ winpack,
                                                  fpp b_in, float* __restrict__ h) {
    __shared__ unsigned short As[128 * 72];
    __shared__ unsigned short Ws[128 * 72];
    int row0 = blockIdx.x * 128;
    int t = threadIdx.x, lane = t & 63, w = t >> 6;
    int quad = lane >> 4, l16 = lane & 15;
    int m_off = (w >> 1) * 64, n_off = (w & 1) * 64;

    f32x4 acc[4][4];
    float bias_v[4];
#pragma unroll
    for (int ni = 0; ni < 4; ni++) bias_v[ni] = b_in[n_off + ni * 16 + l16];
#pragma unroll
    for (int mi = 0; mi < 4; mi++)
#pragma unroll
        for (int ni = 0; ni < 4; ni++)
            acc[mi][ni] = (f32x4){bias_v[ni], bias_v[ni], bias_v[ni], bias_v[ni]};

    for (int kc = 0; kc < 3; kc++) {
        __syncthreads();
        for (int i = 0; i < 4; i++) {
            int g = t + i * 256;
            int r = g >> 3, c = g & 7;
            int rg = min(row0 + r, NN - 1);
            *(s16x8*)(As + r * 72 + c * 8) =
                *(const s16x8*)(xb + (size_t)rg * KPAD + kc * 64 + c * 8);
            *(s16x8*)(Ws + r * 72 + c * 8) =
                *(const s16x8*)(winpack + r * KPAD + kc * 64 + c * 8);
        }
        __syncthreads();
#pragma unroll
        for (int ks = 0; ks < 2; ks++) {
            int k0 = ks * 32;
            s16x8 a[4], b[4];
#pragma unroll
            for (int mi = 0; mi < 4; mi++)
                a[mi] = *(const s16x8*)(As + (m_off + mi * 16 + l16) * 72 + k0 + quad * 8);
#pragma unroll
            for (int ni = 0; ni < 4; ni++)
                b[ni] = *(const s16x8*)(Ws + (n_off + ni * 16 + l16) * 72 + k0 + quad * 8);
#pragma unroll
            for (int mi = 0; mi < 4; mi++)
#pragma unroll
                for (int ni = 0; ni < 4; ni++)
                    acc[mi][ni] = __builtin_amdgcn_mfma_f32_16x16x32_bf16(
                        a[mi], b[ni], acc[mi][ni], 0, 0, 0);
        }
    }
#pragma unroll
    for (int mi = 0; mi < 4; mi++)
#pragma unroll
        for (int ni = 0; ni < 4; ni++)
#pragma unroll
            for (int r = 0; r < 4; r++) {
                int m = row0 + m_off + mi * 16 + quad * 4 + r;
                if (m < NN)
                    h[(size_t)m * HID + n_off + ni * 16 + l16] = acc[mi][ni][r];
            }
}

// ---------------- MFMA fused q/k/v/skip ----------------
__global__ __launch_bounds__(256) void k_dense4(const float* __restrict__ h,
                                                const unsigned short* __restrict__ wpackL,
                                                fpp bq, fpp bk, fpp bv, fpp bs,
                                                bf16* __restrict__ qb, bf16* __restrict__ kb,
                                                bf16* __restrict__ vb, bf16* __restrict__ agg) {
    __shared__ unsigned short As[128 * 136];
    __shared__ unsigned short Ws[128 * 136];
    int row0 = blockIdx.x * 128;
    int t = threadIdx.x, lane = t & 63, w = t >> 6;
    int quad = lane >> 4, l16 = lane & 15;
    int m_off = (w >> 1) * 64, n_off = (w & 1) * 64;

    for (int i = 0; i < 8; i++) {
        int g = t + i * 256;
        int r = g >> 4, c = g & 15;
        int rg = min(row0 + r, NN - 1);
        float4 f0 = *(const float4*)(h + (size_t)rg * HID + c * 8);
        float4 f1 = *(const float4*)(h + (size_t)rg * HID + c * 8 + 4);
        s16x8 us;
        us[0] = (short)bfbits(f0.x); us[1] = (short)bfbits(f0.y);
        us[2] = (short)bfbits(f0.z); us[3] = (short)bfbits(f0.w);
        us[4] = (short)bfbits(f1.x); us[5] = (short)bfbits(f1.y);
        us[6] = (short)bfbits(f1.z); us[7] = (short)bfbits(f1.w);
        *(s16x8*)(As + r * 136 + c * 8) = us;
    }
    __syncthreads();

    s16x8 afr[4][4];
#pragma unroll
    for (int ks = 0; ks < 4; ks++)
#pragma unroll
        for (int mi = 0; mi < 4; mi++)
            afr[ks][mi] = *(const s16x8*)(As + (m_off + mi * 16 + l16) * 136 + ks * 32 + quad * 8);

    for (int nc = 0; nc < 4; nc++) {
        const float* bp; bf16* tp;
        if (nc == 0)      { bp = bq; tp = qb; }
        else if (nc == 1) { bp = bk; tp = kb; }
        else if (nc == 2) { bp = bv; tp = vb; }
        else              { bp = bs; tp = agg; }

        __syncthreads();
        for (int i = 0; i < 8; i++) {
            int g = t + i * 256;
            int r = g >> 4, c = g & 15;
            *(s16x8*)(Ws + r * 136 + c * 8) =
                *(const s16x8*)(wpackL + nc * 16384 + r * HID + c * 8);
        }
        __syncthreads();

        f32x4 acc[4][4];
        float bias_v[4];
#pragma unroll
        for (int ni = 0; ni < 4; ni++) bias_v[ni] = bp[n_off + ni * 16 + l16];
#pragma unroll
        for (int mi = 0; mi < 4; mi++)
#pragma unroll
            for (int ni = 0; ni < 4; ni++)
                acc[mi][ni] = (f32x4){bias_v[ni], bias_v[ni], bias_v[ni], bias_v[ni]};

#pragma unroll
        for (int ks = 0; ks < 4; ks++) {
            s16x8 b[4];
#pragma unroll
            for (int ni = 0; ni < 4; ni++)
                b[ni] = *(const s16x8*)(Ws + (n_off + ni * 16 + l16) * 136 + ks * 32 + quad * 8);
#pragma unroll
            for (int mi = 0; mi < 4; mi++)
#pragma unroll
                for (int ni = 0; ni < 4; ni++)
                    acc[mi][ni] = __builtin_amdgcn_mfma_f32_16x16x32_bf16(
                        afr[ks][mi], b[ni], acc[mi][ni], 0, 0, 0);
        }
        __syncthreads();

        unsigned short* Cs = Ws;
#pragma unroll
        for (int mi = 0; mi < 4; mi++)
#pragma unroll
            for (int ni = 0; ni < 4; ni++)
#pragma unroll
                for (int r = 0; r < 4; r++)
                    Cs[(m_off + mi * 16 + quad * 4 + r) * 136 + n_off + ni * 16 + l16] =
                        bfbits(acc[mi][ni][r]);
        __syncthreads();
        for (int i = 0; i < 8; i++) {
            int g = t + i * 256;
            int r = g >> 4, c = g & 15;
            if (row0 + r < NN)
                *(s16x8*)((unsigned short*)tp + (size_t)(row0 + r) * HID + c * 8) =
                    *(const s16x8*)(Cs + r * 136 + c * 8);
        }
    }
}

// ---------------- fused aggregation + residual + LayerNorm ----------------
// one wave per dst node; lane l holds cols {2l,2l+1}; head = l>>3
__global__ void k_agg_ln(const bf16* __restrict__ qb, const bf16* __restrict__ kb,
                         const bf16* __restrict__ vb, const int* __restrict__ pos,
                         const int* __restrict__ deg, const int* __restrict__ esrc,
                         const bf16* __restrict__ agg, float* __restrict__ h,
                         fpp g, fpp b) {
    int wid = (blockIdx.x * blockDim.x + threadIdx.x) >> 6;
    if (wid >= NN) return;
    int lane = threadIdx.x & 63;
    int d = wid;
    unsigned qu = ((const unsigned*)(qb + (size_t)d * HID))[lane];
    float q0 = bflo(qu) * 0.25f, q1 = bfhi(qu) * 0.25f;  // fold 1/sqrt(D)
    int cnt = deg[d];
    int start = pos[d] - cnt;
    float m = -INFINITY, L = 0.f, o0 = 0.f, o1 = 0.f;
    for (int base = 0; base < cnt; base += 64) {
        int nc = min(64, cnt - base);
        int sj = (lane < nc) ? esrc[start + base + lane] : 0;  // lane-parallel index fetch
        int j = 0;
        for (; j + 1 < nc; j += 2) {
            int s0 = __shfl(sj, j, 64);
            int s1 = __shfl(sj, j + 1, 64);
            unsigned ku0 = ((const unsigned*)(kb + (size_t)s0 * HID))[lane];
            unsigned ku1 = ((const unsigned*)(kb + (size_t)s1 * HID))[lane];
            unsigned vu0 = ((const unsigned*)(vb + (size_t)s0 * HID))[lane];
            unsigned vu1 = ((const unsigned*)(vb + (size_t)s1 * HID))[lane];
            float t0 = q0 * bflo(ku0) + q1 * bfhi(ku0);
            float t1 = q0 * bflo(ku1) + q1 * bfhi(ku1);
            t0 += __shfl_xor(t0, 1, 64); t1 += __shfl_xor(t1, 1, 64);
            t0 += __shfl_xor(t0, 2, 64); t1 += __shfl_xor(t1, 2, 64);
            t0 += __shfl_xor(t0, 4, 64); t1 += __shfl_xor(t1, 4, 64);
            float nm = fmaxf(m, fmaxf(t0, t1));
            float corr = __expf(m - nm);
            float p0 = __expf(t0 - nm), p1 = __expf(t1 - nm);
            L = L * corr + p0 + p1;
            o0 = o0 * corr + p0 * bflo(vu0) + p1 * bflo(vu1);
            o1 = o1 * corr + p0 * bfhi(vu0) + p1 * bfhi(vu1);
            m = nm;
        }
        if (j < nc) {
            int s0 = __shfl(sj, j, 64);
            unsigned ku0 = ((const unsigned*)(kb + (size_t)s0 * HID))[lane];
            unsigned vu0 = ((const unsigned*)(vb + (size_t)s0 * HID))[lane];
            float t0 = q0 * bflo(ku0) + q1 * bfhi(ku0);
            t0 += __shfl_xor(t0, 1, 64);
            t0 += __shfl_xor(t0, 2, 64);
            t0 += __shfl_xor(t0, 4, 64);
            float nm = fmaxf(m, t0);
            float corr = __expf(m - nm);
            float p0 = __expf(t0 - nm);
            L = L * corr + p0;
            o0 = o0 * corr + p0 * bflo(vu0);
            o1 = o1 * corr + p0 * bfhi(vu0);
            m = nm;
        }
    }
    float inv = 1.f / (L + 1e-16f);
    unsigned au = ((const unsigned*)(agg + (size_t)d * HID))[lane];
    float2 hv = ((const float2*)(h + (size_t)d * HID))[lane];
    float v0 = hv.x + bflo(au) + o0 * inv;
    float v1 = hv.y + bfhi(au) + o1 * inv;
    float s = v0 + v1, s2 = v0 * v0 + v1 * v1;
    for (int off = 32; off; off >>= 1) {
        s += __shfl_xor(s, off, 64);
        s2 += __shfl_xor(s2, off, 64);
    }
    float mn = s * (1.f / HID);
    float var = s2 * (1.f / HID) - mn * mn;
    float invs = rsqrtf(var + 1e-5f);
    float2 gv = ((const float2*)g)[lane];
    float2 bv = ((const float2*)b)[lane];
    float2 o;
    o.x = (v0 - mn) * invs * gv.x + bv.x;
    o.y = (v1 - mn) * invs * gv.y + bv.y;
    ((float2*)(h + (size_t)d * HID))[lane] = o;
}

// ---------------- MFMA classifier ----------------
__global__ __launch_bounds__(256) void k_classifier(const float* __restrict__ h,
                                                    const unsigned short* __restrict__ wc1t,
                                                    fpp bc1, fpp Wc2, fpp bc2,
                                                    float* __restrict__ out) {
    __shared__ unsigned short As[128 * 136];
    __shared__ unsigned short Ws[64 * 136];
    int row0 = blockIdx.x * 128;
    int t = threadIdx.x, lane = t & 63, w = t >> 6;
    int quad = lane >> 4, l16 = lane & 15;
    int m_off = w * 32;

    for (int i = 0; i < 8; i++) {
        int g = t + i * 256;
        int r = g >> 4, c = g & 15;
        int rg = min(row0 + r, NN - 1);
        float4 f0 = *(const float4*)(h + (size_t)rg * HID + c * 8);
        float4 f1 = *(const float4*)(h + (size_t)rg * HID + c * 8 + 4);
        s16x8 us;
        us[0] = (short)bfbits(f0.x); us[1] = (short)bfbits(f0.y);
        us[2] = (short)bfbits(f0.z); us[3] = (short)bfbits(f0.w);
        us[4] = (short)bfbits(f1.x); us[5] = (short)bfbits(f1.y);
        us[6] = (short)bfbits(f1.z); us[7] = (short)bfbits(f1.w);
        *(s16x8*)(As + r * 136 + c * 8) = us;
    }
    for (int i = 0; i < 4; i++) {
        int g = t + i * 256;
        int r = g >> 4, c = g & 15;
        *(s16x8*)(Ws + r * 136 + c * 8) = *(const s16x8*)(wc1t + r * HID + c * 8);
    }
    __syncthreads();

    f32x4 acc[2][4];
    float bias_v[4];
#pragma unroll
    for (int ni = 0; ni < 4; ni++) bias_v[ni] = bc1[ni * 16 + l16];
#pragma unroll
    for (int mi = 0; mi < 2; mi++)
#pragma unroll
        for (int ni = 0; ni < 4; ni++)
            acc[mi][ni] = (f32x4){bias_v[ni], bias_v[ni], bias_v[ni], bias_v[ni]};

#pragma unroll
    for (int ks = 0; ks < 4; ks++) {
        s16x8 a[2], b[4];
#pragma unroll
        for (int mi = 0; mi < 2; mi++)
            a[mi] = *(const s16x8*)(As + (m_off + mi * 16 + l16) * 136 + ks * 32 + quad * 8);
#pragma unroll
        for (int ni = 0; ni < 4; ni++)
            b[ni] = *(const s16x8*)(Ws + (ni * 16 + l16) * 136 + ks * 32 + quad * 8);
#pragma unroll
        for (int mi = 0; mi < 2; mi++)
#pragma unroll
            for (int ni = 0; ni < 4; ni++)
                acc[mi][ni] = __builtin_amdgcn_mfma_f32_16x16x32_bf16(
                    a[mi], b[ni], acc[mi][ni], 0, 0, 0);
    }
    __syncthreads();
    float* Cs = (float*)As;
#pragma unroll
    for (int mi = 0; mi < 2; mi++)
#pragma unroll
        for (int ni = 0; ni < 4; ni++)
#pragma unroll
            for (int r = 0; r < 4; r++)
                Cs[(m_off + mi * 16 + quad * 4 + r) * 68 + ni * 16 + l16] =
                    fmaxf(acc[mi][ni][r], 0.f);
    __syncthreads();

    int row = t >> 1, half = t & 1;
    float p0 = 0.f, p1 = 0.f;
    for (int c = half * 32; c < half * 32 + 32; c++) {
        float v = Cs[row * 68 + c];
        p0 += v * Wc2[c * NC + 0];
        p1 += v * Wc2[c * NC + 1];
    }
    p0 += __shfl_xor(p0, 1, 64);
    p1 += __shfl_xor(p1, 1, 64);
    if (half == 0 && row0 + row < NN) {
        out[(size_t)(row0 + row) * NC + 0] = p0 + bc2[0];
        out[(size_t)(row0 + row) * NC + 1] = p1 + bc2[1];
    }
}

extern "C" void kernel_launch(void* const* d_in, const int* in_sizes, int n_in,
                              void* d_out, int out_size, void* d_ws, size_t ws_size,
                              hipStream_t stream) {
    fpp x = (fpp)d_in[0];
    const int* ei = (const int*)d_in[1];
    const int* src = ei;
    const int* dst = ei + EE;
    fpp W_in = (fpp)d_in[2];  fpp b_in = (fpp)d_in[3];
    fpp Wq1 = (fpp)d_in[4];   fpp bq1 = (fpp)d_in[5];
    fpp Wk1 = (fpp)d_in[6];   fpp bk1 = (fpp)d_in[7];
    fpp Wv1 = (fpp)d_in[8];   fpp bv1 = (fpp)d_in[9];
    fpp Ws1 = (fpp)d_in[10];  fpp bs1 = (fpp)d_in[11];
    fpp g1 = (fpp)d_in[12];   fpp be1 = (fpp)d_in[13];
    fpp Wq2 = (fpp)d_in[14];  fpp bq2 = (fpp)d_in[15];
    fpp Wk2 = (fpp)d_in[16];  fpp bk2 = (fpp)d_in[17];
    fpp Wv2 = (fpp)d_in[18];  fpp bv2 = (fpp)d_in[19];
    fpp Ws2 = (fpp)d_in[20];  fpp bs2 = (fpp)d_in[21];
    fpp g2 = (fpp)d_in[22];   fpp be2 = (fpp)d_in[23];
    fpp Wc1 = (fpp)d_in[24];  fpp bc1 = (fpp)d_in[25];
    fpp Wc2 = (fpp)d_in[26];  fpp bc2 = (fpp)d_in[27];
    float* out = (float*)d_out;

    // workspace layout (~156.5 MB)
    char* p = (char*)d_ws;
    float* h = (float*)p;            p += (size_t)NN * HID * 4;   // 51.2 MB
    bf16* agg = (bf16*)p;            p += (size_t)NN * HID * 2;   // 25.6 MB
    bf16* qb = (bf16*)p;             p += (size_t)NN * HID * 2;   // 25.6 MB
    bf16* kb = (bf16*)p;             p += (size_t)NN * HID * 2;   // 25.6 MB
    bf16* vb = (bf16*)p;             p += (size_t)NN * HID * 2;   // 25.6 MB
    int* deg = (int*)p;              p += (size_t)NN * 4;
    int* pos = (int*)p;              p += (size_t)NN * 4;
    int* esrc = (int*)p;             p += (size_t)EE * 4;
    int* bsum = (int*)p;             p += 512 * 4;
    unsigned short* winpack = (unsigned short*)p;  p += 24576 * 2;
    unsigned short* wpack = (unsigned short*)p;    p += 131072 * 2;
    unsigned short* wc1t = (unsigned short*)p;     p += 8192 * 2;
    unsigned short* xb = (unsigned short*)qb;      // aliases qb+kb, dead until layer-1 dense4

    const int nE = (EE + 255) / 256;
    const int nNn = (NN + 255) / 256;

    k_cvt_weights<<<640, 256, 0, stream>>>(W_in, Wq1, Wk1, Wv1, Ws1,
                                           Wq2, Wk2, Wv2, Ws2, Wc1,
                                           winpack, wpack, wc1t);
    k_cvt_x<<<9375, 256, 0, stream>>>(x, xb);

    k_deg_zero<<<nNn, 256, 0, stream>>>(deg);
    k_hist<<<nE, 256, 0, stream>>>(dst, deg);
    k_scan1<<<NBLK, SCANB, 0, stream>>>(deg, pos, bsum, NN);
    k_scan2<<<1, 512, 0, stream>>>(bsum, NBLK);
    k_scan3<<<NBLK, SCANB, 0, stream>>>(pos, bsum, NN);
    k_fill<<<nE, 256, 0, stream>>>(src, dst, pos, esrc);

    k_dense_in<<<NBD2, 256, 0, stream>>>(xb, winpack, b_in, h);

    for (int layer = 0; layer < 2; layer++) {
        fpp bq = layer ? bq2 : bq1, bk = layer ? bk2 : bk1;
        fpp bv = layer ? bv2 : bv1, bs = layer ? bs2 : bs1;
        fpp g = layer ? g2 : g1, be = layer ? be2 : be1;
        const unsigned short* wpackL = wpack + (size_t)layer * 65536;

        k_dense4<<<NBD2, 256, 0, stream>>>(h, wpackL, bq, bk, bv, bs, qb, kb, vb, agg);
        k_agg_ln<<<(NN * 64 + 255) / 256, 256, 0, stream>>>(qb, kb, vb, pos, deg, esrc,
                                                            agg, h, g, be);
    }

    k_classifier<<<NBD2, 256, 0, stream>>>(h, wc1t, bc1, Wc2, bc2, out);
}

// Round 7
// 426.531 us; speedup vs baseline: 3.2745x; 1.0524x over previous
//
#include <hip/hip_runtime.h>
#include <hip/hip_bf16.h>

#define NN 100000
#define EE 400000
#define IN_DIM 165
#define KPAD 192
#define HID 128
#define C1 64
#define NC 2
#define SCANB 256
#define NBLK 391   // ceil(100000/256)
#define NBD2 782   // ceil(100000/128)

typedef const float* fpp;
typedef __hip_bfloat16 bf16;
typedef __attribute__((ext_vector_type(8))) short s16x8;
typedef __attribute__((ext_vector_type(4))) float f32x4;

__device__ __forceinline__ float bflo(unsigned u) { return __uint_as_float(u << 16); }
__device__ __forceinline__ float bfhi(unsigned u) { return __uint_as_float(u & 0xFFFF0000u); }
__device__ __forceinline__ unsigned short bfbits(float f) {
    bf16 h = __float2bfloat16(f);
    return *reinterpret_cast<unsigned short*>(&h);
}

// ---------------- weight conversion / packing (bf16, transposed) ----------------
__global__ void k_cvt_weights(fpp W_in, fpp Wq1, fpp Wk1, fpp Wv1, fpp Ws1,
                              fpp Wq2, fpp Wk2, fpp Wv2, fpp Ws2, fpp Wc1,
                              unsigned short* __restrict__ winpack,
                              unsigned short* __restrict__ wpack,
                              unsigned short* __restrict__ wc1t) {
    int idx = blockIdx.x * blockDim.x + threadIdx.x;
    if (idx < 24576) {
        int n = idx / KPAD, k = idx % KPAD;
        float v = (k < IN_DIM) ? W_in[k * HID + n] : 0.f;
        winpack[idx] = bfbits(v);
    } else if (idx < 155648) {
        int local = idx - 24576;
        int j = local >> 14;
        int l14 = local & 16383;
        int n = l14 >> 7, k = l14 & 127;
        const float* src;
        switch (j) {
            case 0: src = Wq1; break; case 1: src = Wk1; break;
            case 2: src = Wv1; break; case 3: src = Ws1; break;
            case 4: src = Wq2; break; case 5: src = Wk2; break;
            case 6: src = Wv2; break; default: src = Ws2; break;
        }
        wpack[local] = bfbits(src[k * HID + n]);
    } else {
        int local = idx - 155648;
        int n = local >> 7, k = local & 127;
        wc1t[local] = bfbits(Wc1[k * C1 + n]);
    }
}

// x[N,165] fp32 -> xb[N,192] bf16 (zero-padded)
__global__ void k_cvt_x(fpp x, unsigned short* __restrict__ xb) {
    int i = blockIdx.x * blockDim.x + threadIdx.x;  // over N*24
    int row = i / 24, c = i % 24;
    s16x8 us;
#pragma unroll
    for (int j = 0; j < 8; j++) {
        int col = c * 8 + j;
        float v = (col < IN_DIM) ? x[(size_t)row * IN_DIM + col] : 0.f;
        us[j] = (short)bfbits(v);
    }
    *(s16x8*)(xb + (size_t)row * KPAD + c * 8) = us;
}

// ---------------- CSR build ----------------
__global__ void k_hist(const int* __restrict__ dst, int* __restrict__ deg) {
    int e = blockIdx.x * blockDim.x + threadIdx.x;
    if (e < EE) atomicAdd(&deg[dst[e]], 1);
}
__global__ void k_scan1(const int* __restrict__ deg, int* __restrict__ pos,
                        int* __restrict__ bsum, int n) {
    __shared__ int tmp[SCANB];
    int t = threadIdx.x, i = blockIdx.x * SCANB + t;
    int v = (i < n) ? deg[i] : 0;
    tmp[t] = v; __syncthreads();
    for (int off = 1; off < SCANB; off <<= 1) {
        int x = (t >= off) ? tmp[t - off] : 0;
        __syncthreads();
        tmp[t] += x;
        __syncthreads();
    }
    if (i < n) pos[i] = tmp[t] - v;
    if (t == SCANB - 1) bsum[blockIdx.x] = tmp[t];
}
__global__ void k_scan2(int* __restrict__ bsum, int nb) {
    __shared__ int tmp[512];
    int t = threadIdx.x;
    int v = (t < nb) ? bsum[t] : 0;
    tmp[t] = v; __syncthreads();
    for (int off = 1; off < 512; off <<= 1) {
        int x = (t >= off) ? tmp[t - off] : 0;
        __syncthreads();
        tmp[t] += x;
        __syncthreads();
    }
    if (t < nb) bsum[t] = tmp[t] - v;
}
__global__ void k_scan3(int* __restrict__ pos, const int* __restrict__ bsum, int n) {
    int i = blockIdx.x * blockDim.x + threadIdx.x;
    if (i < n) pos[i] += bsum[blockIdx.x];
}
__global__ void k_fill(const int* __restrict__ src, const int* __restrict__ dst,
                       int* __restrict__ pos, int* __restrict__ esrc) {
    int e = blockIdx.x * blockDim.x + threadIdx.x;
    if (e < EE) {
        int p = atomicAdd(&pos[dst[e]], 1);
        esrc[p] = src[e];
    }
}
// pack {start,cnt} per node (pos holds segment END after k_fill)
__global__ void k_pack_csr(const int* __restrict__ pos, const int* __restrict__ deg,
                           int2* __restrict__ csr2) {
    int i = blockIdx.x * blockDim.x + threadIdx.x;
    if (i < NN) {
        int c = deg[i];
        csr2[i] = make_int2(pos[i] - c, c);
    }
}

// ---------------- MFMA input projection: hb = xb @ winpack^T + b_in (bf16 out) ----------------
__global__ __launch_bounds__(256) void k_dense_in(const unsigned short* __restrict__ xb,
                                                  const unsigned short* __restrict__ winpack,
                                                  fpp b_in, unsigned short* __restrict__ hb) {
    __shared__ unsigned short smem[18432];  // As[128*72] | Ws[128*72]; reused as Cs[128*136]
    unsigned short* As = smem;
    unsigned short* Ws = smem + 9216;
    int row0 = blockIdx.x * 128;
    int t = threadIdx.x, lane = t & 63, w = t >> 6;
    int quad = lane >> 4, l16 = lane & 15;
    int m_off = (w >> 1) * 64, n_off = (w & 1) * 64;

    f32x4 acc[4][4];
    float bias_v[4];
#pragma unroll
    for (int ni = 0; ni < 4; ni++) bias_v[ni] = b_in[n_off + ni * 16 + l16];
#pragma unroll
    for (int mi = 0; mi < 4; mi++)
#pragma unroll
        for (int ni = 0; ni < 4; ni++)
            acc[mi][ni] = (f32x4){bias_v[ni], bias_v[ni], bias_v[ni], bias_v[ni]};

    for (int kc = 0; kc < 3; kc++) {
        __syncthreads();
        for (int i = 0; i < 4; i++) {
            int g = t + i * 256;
            int r = g >> 3, c = g & 7;
            int rg = min(row0 + r, NN - 1);
            *(s16x8*)(As + r * 72 + c * 8) =
                *(const s16x8*)(xb + (size_t)rg * KPAD + kc * 64 + c * 8);
            *(s16x8*)(Ws + r * 72 + c * 8) =
                *(const s16x8*)(winpack + r * KPAD + kc * 64 + c * 8);
        }
        __syncthreads();
#pragma unroll
        for (int ks = 0; ks < 2; ks++) {
            int k0 = ks * 32;
            s16x8 a[4], b[4];
#pragma unroll
            for (int mi = 0; mi < 4; mi++)
                a[mi] = *(const s16x8*)(As + (m_off + mi * 16 + l16) * 72 + k0 + quad * 8);
#pragma unroll
            for (int ni = 0; ni < 4; ni++)
                b[ni] = *(const s16x8*)(Ws + (n_off + ni * 16 + l16) * 72 + k0 + quad * 8);
#pragma unroll
            for (int mi = 0; mi < 4; mi++)
#pragma unroll
                for (int ni = 0; ni < 4; ni++)
                    acc[mi][ni] = __builtin_amdgcn_mfma_f32_16x16x32_bf16(
                        a[mi], b[ni], acc[mi][ni], 0, 0, 0);
        }
    }
    __syncthreads();
    unsigned short* Cs = smem;  // [128][136]
#pragma unroll
    for (int mi = 0; mi < 4; mi++)
#pragma unroll
        for (int ni = 0; ni < 4; ni++)
#pragma unroll
            for (int r = 0; r < 4; r++)
                Cs[(m_off + mi * 16 + quad * 4 + r) * 136 + n_off + ni * 16 + l16] =
                    bfbits(acc[mi][ni][r]);
    __syncthreads();
    for (int i = 0; i < 8; i++) {
        int g = t + i * 256;
        int r = g >> 4, c = g & 15;
        if (row0 + r < NN)
            *(s16x8*)(hb + (size_t)(row0 + r) * HID + c * 8) =
                *(const s16x8*)(Cs + r * 136 + c * 8);
    }
}

// ---------------- MFMA fused q/k/v/skip (A = hb bf16, direct copy) ----------------
__global__ __launch_bounds__(256) void k_dense4(const unsigned short* __restrict__ hb,
                                                const unsigned short* __restrict__ wpackL,
                                                fpp bq, fpp bk, fpp bv, fpp bs,
                                                bf16* __restrict__ qb, bf16* __restrict__ kb,
                                                bf16* __restrict__ vb, bf16* __restrict__ agg) {
    __shared__ unsigned short As[128 * 136];
    __shared__ unsigned short Ws[128 * 136];
    int row0 = blockIdx.x * 128;
    int t = threadIdx.x, lane = t & 63, w = t >> 6;
    int quad = lane >> 4, l16 = lane & 15;
    int m_off = (w >> 1) * 64, n_off = (w & 1) * 64;

    for (int i = 0; i < 8; i++) {
        int g = t + i * 256;
        int r = g >> 4, c = g & 15;
        int rg = min(row0 + r, NN - 1);
        *(s16x8*)(As + r * 136 + c * 8) = *(const s16x8*)(hb + (size_t)rg * HID + c * 8);
    }
    __syncthreads();

    s16x8 afr[4][4];
#pragma unroll
    for (int ks = 0; ks < 4; ks++)
#pragma unroll
        for (int mi = 0; mi < 4; mi++)
            afr[ks][mi] = *(const s16x8*)(As + (m_off + mi * 16 + l16) * 136 + ks * 32 + quad * 8);

    for (int nc = 0; nc < 4; nc++) {
        const float* bp; bf16* tp;
        if (nc == 0)      { bp = bq; tp = qb; }
        else if (nc == 1) { bp = bk; tp = kb; }
        else if (nc == 2) { bp = bv; tp = vb; }
        else              { bp = bs; tp = agg; }

        __syncthreads();
        for (int i = 0; i < 8; i++) {
            int g = t + i * 256;
            int r = g >> 4, c = g & 15;
            *(s16x8*)(Ws + r * 136 + c * 8) =
                *(const s16x8*)(wpackL + nc * 16384 + r * HID + c * 8);
        }
        __syncthreads();

        f32x4 acc[4][4];
        float bias_v[4];
#pragma unroll
        for (int ni = 0; ni < 4; ni++) bias_v[ni] = bp[n_off + ni * 16 + l16];
#pragma unroll
        for (int mi = 0; mi < 4; mi++)
#pragma unroll
            for (int ni = 0; ni < 4; ni++)
                acc[mi][ni] = (f32x4){bias_v[ni], bias_v[ni], bias_v[ni], bias_v[ni]};

#pragma unroll
        for (int ks = 0; ks < 4; ks++) {
            s16x8 b[4];
#pragma unroll
            for (int ni = 0; ni < 4; ni++)
                b[ni] = *(const s16x8*)(Ws + (n_off + ni * 16 + l16) * 136 + ks * 32 + quad * 8);
#pragma unroll
            for (int mi = 0; mi < 4; mi++)
#pragma unroll
                for (int ni = 0; ni < 4; ni++)
                    acc[mi][ni] = __builtin_amdgcn_mfma_f32_16x16x32_bf16(
                        afr[ks][mi], b[ni], acc[mi][ni], 0, 0, 0);
        }
        __syncthreads();

        unsigned short* Cs = Ws;
#pragma unroll
        for (int mi = 0; mi < 4; mi++)
#pragma unroll
            for (int ni = 0; ni < 4; ni++)
#pragma unroll
                for (int r = 0; r < 4; r++)
                    Cs[(m_off + mi * 16 + quad * 4 + r) * 136 + n_off + ni * 16 + l16] =
                        bfbits(acc[mi][ni][r]);
        __syncthreads();
        for (int i = 0; i < 8; i++) {
            int g = t + i * 256;
            int r = g >> 4, c = g & 15;
            if (row0 + r < NN)
                *(s16x8*)((unsigned short*)tp + (size_t)(row0 + r) * HID + c * 8) =
                    *(const s16x8*)(Cs + r * 136 + c * 8);
        }
    }
}

// ---------------- fused aggregation + residual + LayerNorm (h bf16 in place) ----------------
__global__ void k_agg_ln(const bf16* __restrict__ qb, const bf16* __restrict__ kb,
                         const bf16* __restrict__ vb, const int2* __restrict__ csr2,
                         const int* __restrict__ esrc, const bf16* __restrict__ agg,
                         unsigned short* __restrict__ hb, fpp g, fpp b) {
    int wid = (blockIdx.x * blockDim.x + threadIdx.x) >> 6;
    if (wid >= NN) return;
    int lane = threadIdx.x & 63;
    int d = wid;
    unsigned qu = ((const unsigned*)(qb + (size_t)d * HID))[lane];
    float q0 = bflo(qu) * 0.25f, q1 = bfhi(qu) * 0.25f;  // fold 1/sqrt(D)
    int2 se = csr2[d];
    int start = se.x, cnt = se.y;
    float m = -INFINITY, L = 0.f, o0 = 0.f, o1 = 0.f;
    for (int base = 0; base < cnt; base += 64) {
        int nc = min(64, cnt - base);
        int sj = (lane < nc) ? esrc[start + base + lane] : 0;
        int j = 0;
        for (; j + 1 < nc; j += 2) {
            int s0 = __shfl(sj, j, 64);
            int s1 = __shfl(sj, j + 1, 64);
            unsigned ku0 = ((const unsigned*)(kb + (size_t)s0 * HID))[lane];
            unsigned ku1 = ((const unsigned*)(kb + (size_t)s1 * HID))[lane];
            unsigned vu0 = ((const unsigned*)(vb + (size_t)s0 * HID))[lane];
            unsigned vu1 = ((const unsigned*)(vb + (size_t)s1 * HID))[lane];
            float t0 = q0 * bflo(ku0) + q1 * bfhi(ku0);
            float t1 = q0 * bflo(ku1) + q1 * bfhi(ku1);
            t0 += __shfl_xor(t0, 1, 64); t1 += __shfl_xor(t1, 1, 64);
            t0 += __shfl_xor(t0, 2, 64); t1 += __shfl_xor(t1, 2, 64);
            t0 += __shfl_xor(t0, 4, 64); t1 += __shfl_xor(t1, 4, 64);
            float nm = fmaxf(m, fmaxf(t0, t1));
            float corr = __expf(m - nm);
            float p0 = __expf(t0 - nm), p1 = __expf(t1 - nm);
            L = L * corr + p0 + p1;
            o0 = o0 * corr + p0 * bflo(vu0) + p1 * bflo(vu1);
            o1 = o1 * corr + p0 * bfhi(vu0) + p1 * bfhi(vu1);
            m = nm;
        }
        if (j < nc) {
            int s0 = __shfl(sj, j, 64);
            unsigned ku0 = ((const unsigned*)(kb + (size_t)s0 * HID))[lane];
            unsigned vu0 = ((const unsigned*)(vb + (size_t)s0 * HID))[lane];
            float t0 = q0 * bflo(ku0) + q1 * bfhi(ku0);
            t0 += __shfl_xor(t0, 1, 64);
            t0 += __shfl_xor(t0, 2, 64);
            t0 += __shfl_xor(t0, 4, 64);
            float nm = fmaxf(m, t0);
            float corr = __expf(m - nm);
            float p0 = __expf(t0 - nm);
            L = L * corr + p0;
            o0 = o0 * corr + p0 * bflo(vu0);
            o1 = o1 * corr + p0 * bfhi(vu0);
            m = nm;
        }
    }
    float inv = 1.f / (L + 1e-16f);
    unsigned au = ((const unsigned*)(agg + (size_t)d * HID))[lane];
    unsigned hu = ((const unsigned*)(hb + (size_t)d * HID))[lane];
    float v0 = bflo(hu) + bflo(au) + o0 * inv;
    float v1 = bfhi(hu) + bfhi(au) + o1 * inv;
    float s = v0 + v1, s2 = v0 * v0 + v1 * v1;
    for (int off = 32; off; off >>= 1) {
        s += __shfl_xor(s, off, 64);
        s2 += __shfl_xor(s2, off, 64);
    }
    float mn = s * (1.f / HID);
    float var = s2 * (1.f / HID) - mn * mn;
    float invs = rsqrtf(var + 1e-5f);
    float2 gv = ((const float2*)g)[lane];
    float2 bv = ((const float2*)b)[lane];
    float ox = (v0 - mn) * invs * gv.x + bv.x;
    float oy = (v1 - mn) * invs * gv.y + bv.y;
    ((unsigned*)(hb + (size_t)d * HID))[lane] = ((unsigned)bfbits(oy) << 16) | bfbits(ox);
}

// ---------------- MFMA classifier ----------------
__global__ __launch_bounds__(256) void k_classifier(const unsigned short* __restrict__ hb,
                                                    const unsigned short* __restrict__ wc1t,
                                                    fpp bc1, fpp Wc2, fpp bc2,
                                                    float* __restrict__ out) {
    __shared__ unsigned short As[128 * 136];
    __shared__ unsigned short Ws[64 * 136];
    int row0 = blockIdx.x * 128;
    int t = threadIdx.x, lane = t & 63, w = t >> 6;
    int quad = lane >> 4, l16 = lane & 15;
    int m_off = w * 32;

    for (int i = 0; i < 8; i++) {
        int g = t + i * 256;
        int r = g >> 4, c = g & 15;
        int rg = min(row0 + r, NN - 1);
        *(s16x8*)(As + r * 136 + c * 8) = *(const s16x8*)(hb + (size_t)rg * HID + c * 8);
    }
    for (int i = 0; i < 4; i++) {
        int g = t + i * 256;
        int r = g >> 4, c = g & 15;
        *(s16x8*)(Ws + r * 136 + c * 8) = *(const s16x8*)(wc1t + r * HID + c * 8);
    }
    __syncthreads();

    f32x4 acc[2][4];
    float bias_v[4];
#pragma unroll
    for (int ni = 0; ni < 4; ni++) bias_v[ni] = bc1[ni * 16 + l16];
#pragma unroll
    for (int mi = 0; mi < 2; mi++)
#pragma unroll
        for (int ni = 0; ni < 4; ni++)
            acc[mi][ni] = (f32x4){bias_v[ni], bias_v[ni], bias_v[ni], bias_v[ni]};

#pragma unroll
    for (int ks = 0; ks < 4; ks++) {
        s16x8 a[2], b[4];
#pragma unroll
        for (int mi = 0; mi < 2; mi++)
            a[mi] = *(const s16x8*)(As + (m_off + mi * 16 + l16) * 136 + ks * 32 + quad * 8);
#pragma unroll
        for (int ni = 0; ni < 4; ni++)
            b[ni] = *(const s16x8*)(Ws + (ni * 16 + l16) * 136 + ks * 32 + quad * 8);
#pragma unroll
        for (int mi = 0; mi < 2; mi++)
#pragma unroll
            for (int ni = 0; ni < 4; ni++)
                acc[mi][ni] = __builtin_amdgcn_mfma_f32_16x16x32_bf16(
                    a[mi], b[ni], acc[mi][ni], 0, 0, 0);
    }
    __syncthreads();
    float* Cs = (float*)As;
#pragma unroll
    for (int mi = 0; mi < 2; mi++)
#pragma unroll
        for (int ni = 0; ni < 4; ni++)
#pragma unroll
            for (int r = 0; r < 4; r++)
                Cs[(m_off + mi * 16 + quad * 4 + r) * 68 + ni * 16 + l16] =
                    fmaxf(acc[mi][ni][r], 0.f);
    __syncthreads();

    int row = t >> 1, half = t & 1;
    float p0 = 0.f, p1 = 0.f;
    for (int c = half * 32; c < half * 32 + 32; c++) {
        float v = Cs[row * 68 + c];
        p0 += v * Wc2[c * NC + 0];
        p1 += v * Wc2[c * NC + 1];
    }
    p0 += __shfl_xor(p0, 1, 64);
    p1 += __shfl_xor(p1, 1, 64);
    if (half == 0 && row0 + row < NN) {
        out[(size_t)(row0 + row) * NC + 0] = p0 + bc2[0];
        out[(size_t)(row0 + row) * NC + 1] = p1 + bc2[1];
    }
}

extern "C" void kernel_launch(void* const* d_in, const int* in_sizes, int n_in,
                              void* d_out, int out_size, void* d_ws, size_t ws_size,
                              hipStream_t stream) {
    fpp x = (fpp)d_in[0];
    const int* ei = (const int*)d_in[1];
    const int* src = ei;
    const int* dst = ei + EE;
    fpp W_in = (fpp)d_in[2];  fpp b_in = (fpp)d_in[3];
    fpp Wq1 = (fpp)d_in[4];   fpp bq1 = (fpp)d_in[5];
    fpp Wk1 = (fpp)d_in[6];   fpp bk1 = (fpp)d_in[7];
    fpp Wv1 = (fpp)d_in[8];   fpp bv1 = (fpp)d_in[9];
    fpp Ws1 = (fpp)d_in[10];  fpp bs1 = (fpp)d_in[11];
    fpp g1 = (fpp)d_in[12];   fpp be1 = (fpp)d_in[13];
    fpp Wq2 = (fpp)d_in[14];  fpp bq2 = (fpp)d_in[15];
    fpp Wk2 = (fpp)d_in[16];  fpp bk2 = (fpp)d_in[17];
    fpp Wv2 = (fpp)d_in[18];  fpp bv2 = (fpp)d_in[19];
    fpp Ws2 = (fpp)d_in[20];  fpp bs2 = (fpp)d_in[21];
    fpp g2 = (fpp)d_in[22];   fpp be2 = (fpp)d_in[23];
    fpp Wc1 = (fpp)d_in[24];  fpp bc1 = (fpp)d_in[25];
    fpp Wc2 = (fpp)d_in[26];  fpp bc2 = (fpp)d_in[27];
    float* out = (float*)d_out;

    // workspace layout (~134 MB)
    char* p = (char*)d_ws;
    unsigned short* hb = (unsigned short*)p;  p += (size_t)NN * HID * 2;  // 25.6 MB
    bf16* agg = (bf16*)p;            p += (size_t)NN * HID * 2;   // 25.6 MB
    bf16* qb = (bf16*)p;             p += (size_t)NN * HID * 2;   // 25.6 MB
    bf16* kb = (bf16*)p;             p += (size_t)NN * HID * 2;   // 25.6 MB
    bf16* vb = (bf16*)p;             p += (size_t)NN * HID * 2;   // 25.6 MB
    int* deg = (int*)p;              p += (size_t)NN * 4;
    int* pos = (int*)p;              p += (size_t)NN * 4;
    int2* csr2 = (int2*)p;           p += (size_t)NN * 8;
    int* esrc = (int*)p;             p += (size_t)EE * 4;
    int* bsum = (int*)p;             p += 512 * 4;
    unsigned short* winpack = (unsigned short*)p;  p += 24576 * 2;
    unsigned short* wpack = (unsigned short*)p;    p += 131072 * 2;
    unsigned short* wc1t = (unsigned short*)p;     p += 8192 * 2;
    unsigned short* xb = (unsigned short*)qb;      // aliases qb+kb, dead until layer-1 dense4

    const int nE = (EE + 255) / 256;
    const int nNn = (NN + 255) / 256;

    k_cvt_weights<<<640, 256, 0, stream>>>(W_in, Wq1, Wk1, Wv1, Ws1,
                                           Wq2, Wk2, Wv2, Ws2, Wc1,
                                           winpack, wpack, wc1t);
    k_cvt_x<<<9375, 256, 0, stream>>>(x, xb);

    hipMemsetAsync(deg, 0, (size_t)NN * 4, stream);
    k_hist<<<nE, 256, 0, stream>>>(dst, deg);
    k_scan1<<<NBLK, SCANB, 0, stream>>>(deg, pos, bsum, NN);
    k_scan2<<<1, 512, 0, stream>>>(bsum, NBLK);
    k_scan3<<<NBLK, SCANB, 0, stream>>>(pos, bsum, NN);
    k_fill<<<nE, 256, 0, stream>>>(src, dst, pos, esrc);
    k_pack_csr<<<nNn, 256, 0, stream>>>(pos, deg, csr2);

    k_dense_in<<<NBD2, 256, 0, stream>>>(xb, winpack, b_in, hb);

    for (int layer = 0; layer < 2; layer++) {
        fpp bq = layer ? bq2 : bq1, bk = layer ? bk2 : bk1;
        fpp bv = layer ? bv2 : bv1, bs = layer ? bs2 : bs1;
        fpp g = layer ? g2 : g1, be = layer ? be2 : be1;
        const unsigned short* wpackL = wpack + (size_t)layer * 65536;

        k_dense4<<<NBD2, 256, 0, stream>>>(hb, wpackL, bq, bk, bv, bs, qb, kb, vb, agg);
        k_agg_ln<<<(NN * 64 + 255) / 256, 256, 0, stream>>>(qb, kb, vb, csr2, esrc,
                                                            agg, hb, g, be);
    }

    k_classifier<<<NBD2, 256, 0, stream>>>(hb, wc1t, bc1, Wc2, bc2, out);
}

// Round 8
// 404.051 us; speedup vs baseline: 3.4567x; 1.0556x over previous
//
#include <hip/hip_runtime.h>
#include <hip/hip_bf16.h>

#define NN 100000
#define EE 400000
#define IN_DIM 165
#define KPAD 192
#define HID 128
#define C1 64
#define NC 2
#define SCANB 256
#define NBLK 391   // ceil(100000/256)
#define NBD2 782   // ceil(100000/128)

typedef const float* fpp;
typedef __hip_bfloat16 bf16;
typedef __attribute__((ext_vector_type(8))) short s16x8;
typedef __attribute__((ext_vector_type(4))) float f32x4;

__device__ __forceinline__ float bflo(unsigned u) { return __uint_as_float(u << 16); }
__device__ __forceinline__ float bfhi(unsigned u) { return __uint_as_float(u & 0xFFFF0000u); }
__device__ __forceinline__ unsigned short bfbits(float f) {
    bf16 h = __float2bfloat16(f);
    return *reinterpret_cast<unsigned short*>(&h);
}

// ---------------- weight conversion / packing ----------------
// wpack per layer, 4 chunks of [n=128][k=128]:
//   chunk0 = Wq; chunk3 = Ws;
//   chunk1/2 = interleaved K/V: packed col p=8a+e (a=0..31): e<4 -> K col 4a+e, else V col 4a+e-4
//   chunk1 covers a in [0,16), chunk2 a in [16,32)
__global__ void k_cvt_weights(fpp W_in, fpp Wq1, fpp Wk1, fpp Wv1, fpp Ws1,
                              fpp Wq2, fpp Wk2, fpp Wv2, fpp Ws2, fpp Wc1,
                              fpp bq1, fpp bk1, fpp bv1, fpp bs1,
                              fpp bq2, fpp bk2, fpp bv2, fpp bs2,
                              unsigned short* __restrict__ winpack,
                              unsigned short* __restrict__ wpack,
                              unsigned short* __restrict__ wc1t,
                              float* __restrict__ bpack) {
    int idx = blockIdx.x * blockDim.x + threadIdx.x;
    if (idx < 24576) {
        int n = idx / KPAD, k = idx % KPAD;
        float v = (k < IN_DIM) ? W_in[k * HID + n] : 0.f;
        winpack[idx] = bfbits(v);
    } else if (idx < 155648) {
        int local = idx - 24576;
        int layer = local >> 16;
        int rest = local & 65535;
        int chunk = rest >> 14;
        int l14 = rest & 16383;
        int n = l14 >> 7, k = l14 & 127;
        const float* src;
        int col;
        if (chunk == 0) { src = layer ? Wq2 : Wq1; col = n; }
        else if (chunk == 3) { src = layer ? Ws2 : Ws1; col = n; }
        else {
            int a = ((chunk == 2) ? 16 : 0) + (n >> 3), e = n & 7;
            src = (e < 4) ? (layer ? Wk2 : Wk1) : (layer ? Wv2 : Wv1);
            col = 4 * a + (e & 3);
        }
        wpack[local] = bfbits(src[k * HID + col]);
    } else if (idx < 163840) {
        int local = idx - 155648;
        int n = local >> 7, k = local & 127;
        wc1t[local] = bfbits(Wc1[k * C1 + n]);
    } else if (idx < 164864) {
        int local = idx - 163840;
        int layer = local >> 9;
        int rest = local & 511;
        int chunk = rest >> 7, n = rest & 127;
        const float* src;
        int col;
        if (chunk == 0) { src = layer ? bq2 : bq1; col = n; }
        else if (chunk == 3) { src = layer ? bs2 : bs1; col = n; }
        else {
            int a = ((chunk == 2) ? 16 : 0) + (n >> 3), e = n & 7;
            src = (e < 4) ? (layer ? bk2 : bk1) : (layer ? bv2 : bv1);
            col = 4 * a + (e & 3);
        }
        bpack[local] = src[col];
    }
}

// x[N,165] fp32 -> xb[N,192] bf16 (zero-padded)
__global__ void k_cvt_x(fpp x, unsigned short* __restrict__ xb) {
    int i = blockIdx.x * blockDim.x + threadIdx.x;  // over N*24
    int row = i / 24, c = i % 24;
    s16x8 us;
#pragma unroll
    for (int j = 0; j < 8; j++) {
        int col = c * 8 + j;
        float v = (col < IN_DIM) ? x[(size_t)row * IN_DIM + col] : 0.f;
        us[j] = (short)bfbits(v);
    }
    *(s16x8*)(xb + (size_t)row * KPAD + c * 8) = us;
}

// ---------------- CSR build ----------------
__global__ void k_hist(const int* __restrict__ dst, int* __restrict__ deg) {
    int e = blockIdx.x * blockDim.x + threadIdx.x;
    if (e < EE) atomicAdd(&deg[dst[e]], 1);
}
__global__ void k_scan1(const int* __restrict__ deg, int* __restrict__ pos,
                        int* __restrict__ bsum, int n) {
    __shared__ int tmp[SCANB];
    int t = threadIdx.x, i = blockIdx.x * SCANB + t;
    int v = (i < n) ? deg[i] : 0;
    tmp[t] = v; __syncthreads();
    for (int off = 1; off < SCANB; off <<= 1) {
        int x = (t >= off) ? tmp[t - off] : 0;
        __syncthreads();
        tmp[t] += x;
        __syncthreads();
    }
    if (i < n) pos[i] = tmp[t] - v;
    if (t == SCANB - 1) bsum[blockIdx.x] = tmp[t];
}
__global__ void k_scan2(int* __restrict__ bsum, int nb) {
    __shared__ int tmp[512];
    int t = threadIdx.x;
    int v = (t < nb) ? bsum[t] : 0;
    tmp[t] = v; __syncthreads();
    for (int off = 1; off < 512; off <<= 1) {
        int x = (t >= off) ? tmp[t - off] : 0;
        __syncthreads();
        tmp[t] += x;
        __syncthreads();
    }
    if (t < nb) bsum[t] = tmp[t] - v;
}
// finalize starts AND write csr2={start,cnt} (before k_fill mutates pos)
__global__ void k_scan3(int* __restrict__ pos, const int* __restrict__ bsum,
                        const int* __restrict__ deg, int2* __restrict__ csr2, int n) {
    int i = blockIdx.x * blockDim.x + threadIdx.x;
    if (i < n) {
        int s = pos[i] + bsum[blockIdx.x];
        pos[i] = s;
        csr2[i] = make_int2(s, deg[i]);
    }
}
__global__ void k_fill(const int* __restrict__ src, const int* __restrict__ dst,
                       int* __restrict__ pos, int* __restrict__ esrc) {
    int e = blockIdx.x * blockDim.x + threadIdx.x;
    if (e < EE) {
        int p = atomicAdd(&pos[dst[e]], 1);
        esrc[p] = src[e];
    }
}

// ---------------- MFMA input projection: hb = xb @ winpack^T + b_in (bf16 out) ----------------
__global__ __launch_bounds__(256) void k_dense_in(const unsigned short* __restrict__ xb,
                                                  const unsigned short* __restrict__ winpack,
                                                  fpp b_in, unsigned short* __restrict__ hb) {
    __shared__ unsigned short smem[18432];  // As[128*72] | Ws[128*72]; reused as Cs[128*136]
    unsigned short* As = smem;
    unsigned short* Ws = smem + 9216;
    int row0 = blockIdx.x * 128;
    int t = threadIdx.x, lane = t & 63, w = t >> 6;
    int quad = lane >> 4, l16 = lane & 15;
    int m_off = (w >> 1) * 64, n_off = (w & 1) * 64;

    f32x4 acc[4][4];
    float bias_v[4];
#pragma unroll
    for (int ni = 0; ni < 4; ni++) bias_v[ni] = b_in[n_off + ni * 16 + l16];
#pragma unroll
    for (int mi = 0; mi < 4; mi++)
#pragma unroll
        for (int ni = 0; ni < 4; ni++)
            acc[mi][ni] = (f32x4){bias_v[ni], bias_v[ni], bias_v[ni], bias_v[ni]};

    for (int kc = 0; kc < 3; kc++) {
        __syncthreads();
        for (int i = 0; i < 4; i++) {
            int g = t + i * 256;
            int r = g >> 3, c = g & 7;
            int rg = min(row0 + r, NN - 1);
            *(s16x8*)(As + r * 72 + c * 8) =
                *(const s16x8*)(xb + (size_t)rg * KPAD + kc * 64 + c * 8);
            *(s16x8*)(Ws + r * 72 + c * 8) =
                *(const s16x8*)(winpack + r * KPAD + kc * 64 + c * 8);
        }
        __syncthreads();
#pragma unroll
        for (int ks = 0; ks < 2; ks++) {
            int k0 = ks * 32;
            s16x8 a[4], b[4];
#pragma unroll
            for (int mi = 0; mi < 4; mi++)
                a[mi] = *(const s16x8*)(As + (m_off + mi * 16 + l16) * 72 + k0 + quad * 8);
#pragma unroll
            for (int ni = 0; ni < 4; ni++)
                b[ni] = *(const s16x8*)(Ws + (n_off + ni * 16 + l16) * 72 + k0 + quad * 8);
#pragma unroll
            for (int mi = 0; mi < 4; mi++)
#pragma unroll
                for (int ni = 0; ni < 4; ni++)
                    acc[mi][ni] = __builtin_amdgcn_mfma_f32_16x16x32_bf16(
                        a[mi], b[ni], acc[mi][ni], 0, 0, 0);
        }
    }
    __syncthreads();
    unsigned short* Cs = smem;  // [128][136]
#pragma unroll
    for (int mi = 0; mi < 4; mi++)
#pragma unroll
        for (int ni = 0; ni < 4; ni++)
#pragma unroll
            for (int r = 0; r < 4; r++)
                Cs[(m_off + mi * 16 + quad * 4 + r) * 136 + n_off + ni * 16 + l16] =
                    bfbits(acc[mi][ni][r]);
    __syncthreads();
    for (int i = 0; i < 8; i++) {
        int g = t + i * 256;
        int r = g >> 4, c = g & 15;
        if (row0 + r < NN)
            *(s16x8*)(hb + (size_t)(row0 + r) * HID + c * 8) =
                *(const s16x8*)(Cs + r * 136 + c * 8);
    }
}

// ---------------- MFMA fused q / kv-packed / skip ----------------
__global__ __launch_bounds__(256) void k_dense4(const unsigned short* __restrict__ hb,
                                                const unsigned short* __restrict__ wpackL,
                                                const float* __restrict__ bpackL,
                                                bf16* __restrict__ qb, bf16* __restrict__ kvb,
                                                bf16* __restrict__ agg) {
    __shared__ unsigned short As[128 * 136];
    __shared__ unsigned short Ws[128 * 136];
    int row0 = blockIdx.x * 128;
    int t = threadIdx.x, lane = t & 63, w = t >> 6;
    int quad = lane >> 4, l16 = lane & 15;
    int m_off = (w >> 1) * 64, n_off = (w & 1) * 64;

    for (int i = 0; i < 8; i++) {
        int g = t + i * 256;
        int r = g >> 4, c = g & 15;
        int rg = min(row0 + r, NN - 1);
        *(s16x8*)(As + r * 136 + c * 8) = *(const s16x8*)(hb + (size_t)rg * HID + c * 8);
    }
    __syncthreads();

    s16x8 afr[4][4];
#pragma unroll
    for (int ks = 0; ks < 4; ks++)
#pragma unroll
        for (int mi = 0; mi < 4; mi++)
            afr[ks][mi] = *(const s16x8*)(As + (m_off + mi * 16 + l16) * 136 + ks * 32 + quad * 8);

    for (int nc = 0; nc < 4; nc++) {
        unsigned short* tp; int stride;
        if (nc == 0)      { tp = (unsigned short*)qb;        stride = 128; }
        else if (nc == 1) { tp = (unsigned short*)kvb;       stride = 256; }
        else if (nc == 2) { tp = (unsigned short*)kvb + 128; stride = 256; }
        else              { tp = (unsigned short*)agg;       stride = 128; }
        const float* bp = bpackL + nc * 128;

        __syncthreads();  // prior Cs consumers done (Cs aliases Ws)
        for (int i = 0; i < 8; i++) {
            int g = t + i * 256;
            int r = g >> 4, c = g & 15;
            *(s16x8*)(Ws + r * 136 + c * 8) =
                *(const s16x8*)(wpackL + nc * 16384 + r * HID + c * 8);
        }
        __syncthreads();

        f32x4 acc[4][4];
        float bias_v[4];
#pragma unroll
        for (int ni = 0; ni < 4; ni++) bias_v[ni] = bp[n_off + ni * 16 + l16];
#pragma unroll
        for (int mi = 0; mi < 4; mi++)
#pragma unroll
            for (int ni = 0; ni < 4; ni++)
                acc[mi][ni] = (f32x4){bias_v[ni], bias_v[ni], bias_v[ni], bias_v[ni]};

#pragma unroll
        for (int ks = 0; ks < 4; ks++) {
            s16x8 b[4];
#pragma unroll
            for (int ni = 0; ni < 4; ni++)
                b[ni] = *(const s16x8*)(Ws + (n_off + ni * 16 + l16) * 136 + ks * 32 + quad * 8);
#pragma unroll
            for (int mi = 0; mi < 4; mi++)
#pragma unroll
                for (int ni = 0; ni < 4; ni++)
                    acc[mi][ni] = __builtin_amdgcn_mfma_f32_16x16x32_bf16(
                        afr[ks][mi], b[ni], acc[mi][ni], 0, 0, 0);
        }
        __syncthreads();

        unsigned short* Cs = Ws;
#pragma unroll
        for (int mi = 0; mi < 4; mi++)
#pragma unroll
            for (int ni = 0; ni < 4; ni++)
#pragma unroll
                for (int r = 0; r < 4; r++)
                    Cs[(m_off + mi * 16 + quad * 4 + r) * 136 + n_off + ni * 16 + l16] =
                        bfbits(acc[mi][ni][r]);
        __syncthreads();
        for (int i = 0; i < 8; i++) {
            int g = t + i * 256;
            int r = g >> 4, c = g & 15;
            if (row0 + r < NN)
                *(s16x8*)(tp + (size_t)(row0 + r) * stride + c * 8) =
                    *(const s16x8*)(Cs + r * 136 + c * 8);
        }
    }
}

// ---------------- fused aggregation + residual + LayerNorm ----------------
// TWO nodes per wave (32 lanes each); lane covers 4 cols [4*l32, 4*l32+4)
// head h = cols [16h,16h+16) = lanes [4h,4h+4); kv packed: one uint4 = k+v frags
__global__ void k_agg_ln(const bf16* __restrict__ qb, const bf16* __restrict__ kvb,
                         const int2* __restrict__ csr2, const int* __restrict__ esrc,
                         const bf16* __restrict__ agg, unsigned short* __restrict__ hb,
                         fpp g, fpp b) {
    int wv = (blockIdx.x * blockDim.x + threadIdx.x) >> 6;
    int lane = threadIdx.x & 63;
    int l32 = lane & 31;
    int d = wv * 2 + (lane >> 5);
    if (d >= NN) return;
    uint2 qu = ((const uint2*)(qb + (size_t)d * HID))[l32];
    float q0 = bflo(qu.x) * 0.25f, q1 = bfhi(qu.x) * 0.25f;
    float q2 = bflo(qu.y) * 0.25f, q3 = bfhi(qu.y) * 0.25f;
    int2 se = csr2[d];
    uint2 au = ((const uint2*)(agg + (size_t)d * HID))[l32];
    uint2 hu = ((const uint2*)(hb + (size_t)d * HID))[l32];
    float4 gv = ((const float4*)g)[l32];
    float4 bv = ((const float4*)b)[l32];
    int start = se.x, cnt = se.y;
    float m = -INFINITY, L = 0.f, o0 = 0.f, o1 = 0.f, o2 = 0.f, o3 = 0.f;
    for (int base = 0; base < cnt; base += 32) {
        int nc = min(32, cnt - base);
        int sj = (l32 < nc) ? esrc[start + base + l32] : 0;
        int j = 0;
        for (; j + 1 < nc; j += 2) {
            int s0 = __shfl(sj, j, 32);
            int s1 = __shfl(sj, j + 1, 32);
            uint4 kv0 = ((const uint4*)(kvb + (size_t)s0 * 256))[l32];
            uint4 kv1 = ((const uint4*)(kvb + (size_t)s1 * 256))[l32];
            float t0 = q0 * bflo(kv0.x) + q1 * bfhi(kv0.x) + q2 * bflo(kv0.y) + q3 * bfhi(kv0.y);
            float t1 = q0 * bflo(kv1.x) + q1 * bfhi(kv1.x) + q2 * bflo(kv1.y) + q3 * bfhi(kv1.y);
            t0 += __shfl_xor(t0, 1); t1 += __shfl_xor(t1, 1);
            t0 += __shfl_xor(t0, 2); t1 += __shfl_xor(t1, 2);
            float nm = fmaxf(m, fmaxf(t0, t1));
            float corr = __expf(m - nm);
            float p0 = __expf(t0 - nm), p1 = __expf(t1 - nm);
            L = L * corr + p0 + p1;
            o0 = o0 * corr + p0 * bflo(kv0.z) + p1 * bflo(kv1.z);
            o1 = o1 * corr + p0 * bfhi(kv0.z) + p1 * bfhi(kv1.z);
            o2 = o2 * corr + p0 * bflo(kv0.w) + p1 * bflo(kv1.w);
            o3 = o3 * corr + p0 * bfhi(kv0.w) + p1 * bfhi(kv1.w);
            m = nm;
        }
        if (j < nc) {
            int s0 = __shfl(sj, j, 32);
            uint4 kv0 = ((const uint4*)(kvb + (size_t)s0 * 256))[l32];
            float t0 = q0 * bflo(kv0.x) + q1 * bfhi(kv0.x) + q2 * bflo(kv0.y) + q3 * bfhi(kv0.y);
            t0 += __shfl_xor(t0, 1);
            t0 += __shfl_xor(t0, 2);
            float nm = fmaxf(m, t0);
            float corr = __expf(m - nm);
            float p0 = __expf(t0 - nm);
            L = L * corr + p0;
            o0 = o0 * corr + p0 * bflo(kv0.z);
            o1 = o1 * corr + p0 * bfhi(kv0.z);
            o2 = o2 * corr + p0 * bflo(kv0.w);
            o3 = o3 * corr + p0 * bfhi(kv0.w);
            m = nm;
        }
    }
    float inv = 1.f / (L + 1e-16f);
    float v0 = bflo(hu.x) + bflo(au.x) + o0 * inv;
    float v1 = bfhi(hu.x) + bfhi(au.x) + o1 * inv;
    float v2 = bflo(hu.y) + bflo(au.y) + o2 * inv;
    float v3 = bfhi(hu.y) + bfhi(au.y) + o3 * inv;
    float s = v0 + v1 + v2 + v3;
    float s2 = v0 * v0 + v1 * v1 + v2 * v2 + v3 * v3;
    for (int off = 16; off; off >>= 1) {
        s += __shfl_xor(s, off);
        s2 += __shfl_xor(s2, off);
    }
    float mn = s * (1.f / HID);
    float var = s2 * (1.f / HID) - mn * mn;
    float invs = rsqrtf(var + 1e-5f);
    float ox = (v0 - mn) * invs * gv.x + bv.x;
    float oy = (v1 - mn) * invs * gv.y + bv.y;
    float oz = (v2 - mn) * invs * gv.z + bv.z;
    float ow = (v3 - mn) * invs * gv.w + bv.w;
    uint2 outw;
    outw.x = ((unsigned)bfbits(oy) << 16) | bfbits(ox);
    outw.y = ((unsigned)bfbits(ow) << 16) | bfbits(oz);
    ((uint2*)(hb + (size_t)d * HID))[l32] = outw;
}

// ---------------- MFMA classifier ----------------
__global__ __launch_bounds__(256) void k_classifier(const unsigned short* __restrict__ hb,
                                                    const unsigned short* __restrict__ wc1t,
                                                    fpp bc1, fpp Wc2, fpp bc2,
                                                    float* __restrict__ out) {
    __shared__ unsigned short As[128 * 136];
    __shared__ unsigned short Ws[64 * 136];
    int row0 = blockIdx.x * 128;
    int t = threadIdx.x, lane = t & 63, w = t >> 6;
    int quad = lane >> 4, l16 = lane & 15;
    int m_off = w * 32;

    for (int i = 0; i < 8; i++) {
        int g = t + i * 256;
        int r = g >> 4, c = g & 15;
        int rg = min(row0 + r, NN - 1);
        *(s16x8*)(As + r * 136 + c * 8) = *(const s16x8*)(hb + (size_t)rg * HID + c * 8);
    }
    for (int i = 0; i < 4; i++) {
        int g = t + i * 256;
        int r = g >> 4, c = g & 15;
        *(s16x8*)(Ws + r * 136 + c * 8) = *(const s16x8*)(wc1t + r * HID + c * 8);
    }
    __syncthreads();

    f32x4 acc[2][4];
    float bias_v[4];
#pragma unroll
    for (int ni = 0; ni < 4; ni++) bias_v[ni] = bc1[ni * 16 + l16];
#pragma unroll
    for (int mi = 0; mi < 2; mi++)
#pragma unroll
        for (int ni = 0; ni < 4; ni++)
            acc[mi][ni] = (f32x4){bias_v[ni], bias_v[ni], bias_v[ni], bias_v[ni]};

#pragma unroll
    for (int ks = 0; ks < 4; ks++) {
        s16x8 a[2], b[4];
#pragma unroll
        for (int mi = 0; mi < 2; mi++)
            a[mi] = *(const s16x8*)(As + (m_off + mi * 16 + l16) * 136 + ks * 32 + quad * 8);
#pragma unroll
        for (int ni = 0; ni < 4; ni++)
            b[ni] = *(const s16x8*)(Ws + (ni * 16 + l16) * 136 + ks * 32 + quad * 8);
#pragma unroll
        for (int mi = 0; mi < 2; mi++)
#pragma unroll
            for (int ni = 0; ni < 4; ni++)
                acc[mi][ni] = __builtin_amdgcn_mfma_f32_16x16x32_bf16(
                    a[mi], b[ni], acc[mi][ni], 0, 0, 0);
    }
    __syncthreads();
    float* Cs = (float*)As;
#pragma unroll
    for (int mi = 0; mi < 2; mi++)
#pragma unroll
        for (int ni = 0; ni < 4; ni++)
#pragma unroll
            for (int r = 0; r < 4; r++)
                Cs[(m_off + mi * 16 + quad * 4 + r) * 68 + ni * 16 + l16] =
                    fmaxf(acc[mi][ni][r], 0.f);
    __syncthreads();

    int row = t >> 1, half = t & 1;
    float p0 = 0.f, p1 = 0.f;
    for (int c = half * 32; c < half * 32 + 32; c++) {
        float v = Cs[row * 68 + c];
        p0 += v * Wc2[c * NC + 0];
        p1 += v * Wc2[c * NC + 1];
    }
    p0 += __shfl_xor(p0, 1, 64);
    p1 += __shfl_xor(p1, 1, 64);
    if (half == 0 && row0 + row < NN) {
        out[(size_t)(row0 + row) * NC + 0] = p0 + bc2[0];
        out[(size_t)(row0 + row) * NC + 1] = p1 + bc2[1];
    }
}

extern "C" void kernel_launch(void* const* d_in, const int* in_sizes, int n_in,
                              void* d_out, int out_size, void* d_ws, size_t ws_size,
                              hipStream_t stream) {
    fpp x = (fpp)d_in[0];
    const int* ei = (const int*)d_in[1];
    const int* src = ei;
    const int* dst = ei + EE;
    fpp W_in = (fpp)d_in[2];  fpp b_in = (fpp)d_in[3];
    fpp Wq1 = (fpp)d_in[4];   fpp bq1 = (fpp)d_in[5];
    fpp Wk1 = (fpp)d_in[6];   fpp bk1 = (fpp)d_in[7];
    fpp Wv1 = (fpp)d_in[8];   fpp bv1 = (fpp)d_in[9];
    fpp Ws1 = (fpp)d_in[10];  fpp bs1 = (fpp)d_in[11];
    fpp g1 = (fpp)d_in[12];   fpp be1 = (fpp)d_in[13];
    fpp Wq2 = (fpp)d_in[14];  fpp bq2 = (fpp)d_in[15];
    fpp Wk2 = (fpp)d_in[16];  fpp bk2 = (fpp)d_in[17];
    fpp Wv2 = (fpp)d_in[18];  fpp bv2 = (fpp)d_in[19];
    fpp Ws2 = (fpp)d_in[20];  fpp bs2 = (fpp)d_in[21];
    fpp g2 = (fpp)d_in[22];   fpp be2 = (fpp)d_in[23];
    fpp Wc1 = (fpp)d_in[24];  fpp bc1 = (fpp)d_in[25];
    fpp Wc2 = (fpp)d_in[26];  fpp bc2 = (fpp)d_in[27];
    float* out = (float*)d_out;

    // workspace layout (~132 MB)
    char* p = (char*)d_ws;
    unsigned short* hb = (unsigned short*)p;  p += (size_t)NN * HID * 2;  // 25.6 MB
    bf16* agg = (bf16*)p;            p += (size_t)NN * HID * 2;           // 25.6 MB
    bf16* qb = (bf16*)p;             p += (size_t)NN * HID * 2;           // 25.6 MB
    bf16* kvb = (bf16*)p;            p += (size_t)NN * 256 * 2;           // 51.2 MB
    int* deg = (int*)p;              p += (size_t)NN * 4;
    int* pos = (int*)p;              p += (size_t)NN * 4;
    int2* csr2 = (int2*)p;           p += (size_t)NN * 8;
    int* esrc = (int*)p;             p += (size_t)EE * 4;
    int* bsum = (int*)p;             p += 512 * 4;
    unsigned short* winpack = (unsigned short*)p;  p += 24576 * 2;
    unsigned short* wpack = (unsigned short*)p;    p += 131072 * 2;
    unsigned short* wc1t = (unsigned short*)p;     p += 8192 * 2;
    float* bpack = (float*)p;                      p += 1024 * 4;
    unsigned short* xb = (unsigned short*)qb;  // aliases qb+kvb head; dead before dense4

    const int nE = (EE + 255) / 256;
    const int nNn = (NN + 255) / 256;

    k_cvt_weights<<<644, 256, 0, stream>>>(W_in, Wq1, Wk1, Wv1, Ws1,
                                           Wq2, Wk2, Wv2, Ws2, Wc1,
                                           bq1, bk1, bv1, bs1, bq2, bk2, bv2, bs2,
                                           winpack, wpack, wc1t, bpack);
    k_cvt_x<<<9375, 256, 0, stream>>>(x, xb);

    hipMemsetAsync(deg, 0, (size_t)NN * 4, stream);
    k_hist<<<nE, 256, 0, stream>>>(dst, deg);
    k_scan1<<<NBLK, SCANB, 0, stream>>>(deg, pos, bsum, NN);
    k_scan2<<<1, 512, 0, stream>>>(bsum, NBLK);
    k_scan3<<<NBLK, SCANB, 0, stream>>>(pos, bsum, deg, csr2, NN);
    k_fill<<<nE, 256, 0, stream>>>(src, dst, pos, esrc);

    k_dense_in<<<NBD2, 256, 0, stream>>>(xb, winpack, b_in, hb);

    for (int layer = 0; layer < 2; layer++) {
        fpp g = layer ? g2 : g1, be = layer ? be2 : be1;
        const unsigned short* wpackL = wpack + (size_t)layer * 65536;
        const float* bpackL = bpack + (size_t)layer * 512;

        k_dense4<<<NBD2, 256, 0, stream>>>(hb, wpackL, bpackL, qb, kvb, agg);
        k_agg_ln<<<12500, 256, 0, stream>>>(qb, kvb, csr2, esrc, agg, hb, g, be);
    }

    k_classifier<<<NBD2, 256, 0, stream>>>(hb, wc1t, bc1, Wc2, bc2, out);
}